// Round 1
// baseline (290.582 us; speedup 1.0000x reference)
//
#include <hip/hip_runtime.h>
#include <hip/hip_bf16.h>

#define N_SEC 32
#define BDIM 1024
#define DDIM 1024

typedef __attribute__((ext_vector_type(8))) short bf16x8;
typedef __attribute__((ext_vector_type(4))) float f32x4;
typedef __attribute__((ext_vector_type(4))) int i32x4;

__device__ __forceinline__ unsigned pk2(float a, float b) {
    union { __hip_bfloat162 h; unsigned u; } cv;
    cv.h = __float22bfloat162_rn(make_float2(a, b));
    return cv.u;
}

__device__ __forceinline__ i32x4 pack8(float4 a, float4 b) {
    i32x4 r;
    r[0] = pk2(a.x, a.y); r[1] = pk2(a.z, a.w);
    r[2] = pk2(b.x, b.y); r[3] = pk2(b.z, b.w);
    return r;
}

__device__ __forceinline__ f32x4 mfma16(bf16x8 a, bf16x8 b, f32x4 c) {
    return __builtin_amdgcn_mfma_f32_16x16x32_bf16(a, b, c, 0, 0, 0);
}

__device__ __forceinline__ float wave_sum(float v) {
    #pragma unroll
    for (int off = 32; off > 0; off >>= 1) v += __shfl_down(v, off, 64);
    return v;
}

// Row norms of bf16-rounded data (consistent with the MFMA grams).
// rows [0, 32768): outputs flattened [N*B]; rows [32768, 33792): encode [B].
__global__ void norms_k(const float* __restrict__ outp, const float* __restrict__ enc,
                        float* __restrict__ sq_out, float* __restrict__ sq_enc) {
    int wid = threadIdx.x >> 6, l = threadIdx.x & 63;
    int r = blockIdx.x * 4 + wid;
    const float* src = (r < N_SEC * BDIM) ? (outp + (size_t)r * DDIM)
                                          : (enc + (size_t)(r - N_SEC * BDIM) * DDIM);
    float s = 0.f;
    #pragma unroll
    for (int q = 0; q < 4; q++) {
        float4 v = reinterpret_cast<const float4*>(src)[l + q * 64];
        unsigned u0 = pk2(v.x, v.y), u1 = pk2(v.z, v.w);
        float a = __uint_as_float(u0 << 16), b = __uint_as_float(u0 & 0xFFFF0000u);
        float c = __uint_as_float(u1 << 16), d = __uint_as_float(u1 & 0xFFFF0000u);
        s += a * a + b * b + c * c + d * d;
    }
    s = wave_sum(s);
    if (l == 0) { if (r < N_SEC * BDIM) sq_out[r] = s; else sq_enc[r - N_SEC * BDIM] = s; }
}

// MODE 0: write d_sent = sqrt(max(d2,0)+eps) for upper tiles of encode gram.
// MODE 1: accumulate sum of 2*(d_out - d_sent)^2 over strict upper triangle.
// 128x128 tile per block, 4 waves (2x2), each wave 64x64 via 4x4 MFMA frags.
// LDS bf16 tiles with 16B-chunk XOR swizzle (chunk ^= row&3) -> conflict-free b128 reads.
template<int MODE>
__global__ void gram_k(const float* __restrict__ X, const float* __restrict__ sqv,
                       const float* __restrict__ dsent_r, float* __restrict__ dsent_w,
                       float* __restrict__ accum) {
    int idx = blockIdx.x, ti = 0;
    while (idx >= 8 - ti) { idx -= 8 - ti; ti++; }
    int tj = ti + idx;
    int n = (MODE == 1) ? blockIdx.y : 0;
    const float* Xn = X + (size_t)n * BDIM * DDIM;
    const float* sqn = sqv + n * BDIM;
    int i0 = ti * 128, j0 = tj * 128;
    bool diag = (ti == tj);

    __shared__ __align__(16) unsigned short Ash[128 * 32];
    __shared__ __align__(16) unsigned short Bsh[128 * 32];

    int t = threadIdx.x;
    int wid = t >> 6, l = t & 63;
    int wr = wid >> 1, wc = wid & 1;
    bool dead = diag && (wr > wc);   // wave tile fully below diagonal
    int cg = l >> 4, lr = l & 15;

    f32x4 acc[4][4];
    #pragma unroll
    for (int a = 0; a < 4; a++)
        #pragma unroll
        for (int c = 0; c < 4; c++) acc[a][c] = f32x4{0.f, 0.f, 0.f, 0.f};

    int r0 = t >> 2, c0 = t & 3;          // this thread stages rows r0, r0+64, chunk c0
    int swz0 = (c0 ^ (r0 & 3)) * 8;       // (r0+64)&3 == r0&3
    int off0 = r0 * 32 + swz0;
    int off1 = (r0 + 64) * 32 + swz0;

    for (int kt = 0; kt < DDIM / 32; ++kt) {
        int k0 = kt * 32;
        const float4* pa0 = (const float4*)(Xn + (size_t)(i0 + r0) * DDIM + k0 + c0 * 8);
        const float4* pa1 = (const float4*)(Xn + (size_t)(i0 + r0 + 64) * DDIM + k0 + c0 * 8);
        const float4* pb0 = (const float4*)(Xn + (size_t)(j0 + r0) * DDIM + k0 + c0 * 8);
        const float4* pb1 = (const float4*)(Xn + (size_t)(j0 + r0 + 64) * DDIM + k0 + c0 * 8);
        float4 a00 = pa0[0], a01 = pa0[1];
        float4 a10 = pa1[0], a11 = pa1[1];
        float4 b00 = pb0[0], b01 = pb0[1];
        float4 b10 = pb1[0], b11 = pb1[1];
        __syncthreads();
        *(i32x4*)&Ash[off0] = pack8(a00, a01);
        *(i32x4*)&Ash[off1] = pack8(a10, a11);
        *(i32x4*)&Bsh[off0] = pack8(b00, b01);
        *(i32x4*)&Bsh[off1] = pack8(b10, b11);
        __syncthreads();
        if (!dead) {
            bf16x8 af[4], bfr[4];
            #pragma unroll
            for (int f = 0; f < 4; f++) {
                int ra = wr * 64 + f * 16 + lr;
                af[f] = *(const bf16x8*)&Ash[ra * 32 + ((cg ^ (ra & 3)) * 8)];
                int rb = wc * 64 + f * 16 + lr;
                bfr[f] = *(const bf16x8*)&Bsh[rb * 32 + ((cg ^ (rb & 3)) * 8)];
            }
            #pragma unroll
            for (int fi = 0; fi < 4; fi++)
                #pragma unroll
                for (int fj = 0; fj < 4; fj++) {
                    if (diag && wr == wc && fj < fi) continue;  // frag fully below diag
                    acc[fi][fj] = mfma16(af[fi], bfr[fj], acc[fi][fj]);
                }
        }
    }

    if (!dead) {
        float lsum = 0.f;
        #pragma unroll
        for (int fi = 0; fi < 4; fi++) {
            #pragma unroll
            for (int fj = 0; fj < 4; fj++) {
                if (diag && wr == wc && fj < fi) continue;
                int jg = j0 + wc * 64 + fj * 16 + lr;
                #pragma unroll
                for (int e = 0; e < 4; e++) {
                    int ig = i0 + wr * 64 + fi * 16 + cg * 4 + e;
                    float g = acc[fi][fj][e];
                    float d2 = sqn[ig] + sqn[jg] - 2.f * g;
                    float d = sqrtf(fmaxf(d2, 0.f) + 1e-12f);
                    if (MODE == 0) {
                        dsent_w[(size_t)ig * BDIM + jg] = d;
                    } else {
                        if (!diag || jg > ig) {   // guard: never read unwritten dsent
                            float diff = d - dsent_r[(size_t)ig * BDIM + jg];
                            lsum += diff * diff;
                        }
                    }
                }
            }
        }
        if (MODE == 1) {
            lsum = wave_sum(lsum * 2.f);          // upper triangle counted twice
            if (l == 0) atomicAdd(accum, lsum);
        }
    }
}

// Per-b 32x32 gram over D=1024; hinge relu(1-d) over strict upper triangle.
// One wave per b; only blocks (0,0),(0,1),(1,1) of the 2x2 16x16 grid needed.
__global__ void secret_k(const float* __restrict__ X, const float* __restrict__ sq_out,
                         float* __restrict__ accum) {
    int wid = threadIdx.x >> 6, l = threadIdx.x & 63;
    int b = blockIdx.x * 4 + wid;
    int cg = l >> 4, lr = l & 15;
    f32x4 a00 = {0.f,0.f,0.f,0.f}, a01 = {0.f,0.f,0.f,0.f}, a11 = {0.f,0.f,0.f,0.f};
    for (int kt = 0; kt < 32; ++kt) {
        int k0 = kt * 32 + cg * 8;
        const float4* p0 = (const float4*)(X + ((size_t)lr * BDIM + b) * DDIM + k0);
        const float4* p1 = (const float4*)(X + ((size_t)(16 + lr) * BDIM + b) * DDIM + k0);
        union { i32x4 i; bf16x8 s; } u0, u1;
        u0.i = pack8(p0[0], p0[1]);
        u1.i = pack8(p1[0], p1[1]);
        a00 = mfma16(u0.s, u0.s, a00);
        a01 = mfma16(u0.s, u1.s, a01);
        a11 = mfma16(u1.s, u1.s, a11);
    }
    float lsum = 0.f;
    auto proc = [&](const f32x4& acc, int rb, int cb) {
        #pragma unroll
        for (int e = 0; e < 4; e++) {
            int i = rb * 16 + cg * 4 + e;
            int j = cb * 16 + lr;
            if (j > i) {
                float d2 = sq_out[(size_t)i * BDIM + b] + sq_out[(size_t)j * BDIM + b] - 2.f * acc[e];
                float d = sqrtf(fmaxf(d2, 0.f) + 1e-12f);
                lsum += fmaxf(1.f - d, 0.f);
            }
        }
    };
    proc(a00, 0, 0); proc(a01, 0, 1); proc(a11, 1, 1);
    lsum = wave_sum(lsum);
    if (l == 0) atomicAdd(accum, lsum);
}

__global__ void init_k(float* sums) { sums[threadIdx.x] = 0.f; }

__global__ void fin_k(const float* __restrict__ sums, float* __restrict__ out) {
    float sl = sums[0] * (1.0f / 33554432.0f);            // / (N*B*B)
    float sec = sums[1] * (1.0f / (1024.0f * 496.0f));    // / B / n_pairs
    out[0] = 0.5f * sl + 0.5f * sec;
    out[1] = sl;
    out[2] = sec;
}

extern "C" void kernel_launch(void* const* d_in, const int* in_sizes, int n_in,
                              void* d_out, int out_size, void* d_ws, size_t ws_size,
                              hipStream_t stream) {
    const float* outputs = (const float*)d_in[0];   // [32,1024,1024] f32
    const float* enc     = (const float*)d_in[1];   // [1024,1024] f32
    float* out = (float*)d_out;                     // 3 floats

    // ws layout (floats): [0..63] sums+pad, sq_out[32768], sq_enc[1024], dsent[1024*1024]
    float* sums   = (float*)d_ws;
    float* sq_out = sums + 64;
    float* sq_enc = sq_out + N_SEC * BDIM;
    float* dsent  = sq_enc + BDIM;

    hipLaunchKernelGGL(init_k, dim3(1), dim3(2), 0, stream, sums);
    hipLaunchKernelGGL(norms_k, dim3((N_SEC * BDIM + BDIM) / 4), dim3(256), 0, stream,
                       outputs, enc, sq_out, sq_enc);
    hipLaunchKernelGGL((gram_k<0>), dim3(36), dim3(256), 0, stream,
                       enc, sq_enc, (const float*)nullptr, dsent, (float*)nullptr);
    hipLaunchKernelGGL((gram_k<1>), dim3(36, N_SEC), dim3(256), 0, stream,
                       outputs, sq_out, (const float*)dsent, (float*)nullptr, &sums[0]);
    hipLaunchKernelGGL(secret_k, dim3(256), dim3(256), 0, stream,
                       outputs, sq_out, &sums[1]);
    hipLaunchKernelGGL(fin_k, dim3(1), dim3(1), 0, stream, sums, out);
}

// Round 2
// 236.380 us; speedup vs baseline: 1.2293x; 1.2293x over previous
//
#include <hip/hip_runtime.h>
#include <hip/hip_bf16.h>

#define N_SEC 32
#define BDIM 1024
#define DDIM 1024

typedef __attribute__((ext_vector_type(8))) short bf16x8;
typedef __attribute__((ext_vector_type(4))) float f32x4;
typedef __attribute__((ext_vector_type(4))) int i32x4;

__device__ __forceinline__ unsigned pk2(float a, float b) {
    union { __hip_bfloat162 h; unsigned u; } cv;
    cv.h = __float22bfloat162_rn(make_float2(a, b));
    return cv.u;
}

__device__ __forceinline__ i32x4 pack8(float4 a, float4 b) {
    i32x4 r;
    r[0] = pk2(a.x, a.y); r[1] = pk2(a.z, a.w);
    r[2] = pk2(b.x, b.y); r[3] = pk2(b.z, b.w);
    return r;
}

__device__ __forceinline__ f32x4 mfma16(bf16x8 a, bf16x8 b, f32x4 c) {
    return __builtin_amdgcn_mfma_f32_16x16x32_bf16(a, b, c, 0, 0, 0);
}

__device__ __forceinline__ float wave_sum(float v) {
    #pragma unroll
    for (int off = 32; off > 0; off >>= 1) v += __shfl_down(v, off, 64);
    return v;
}

// async global->LDS, 16B per lane. LDS dest is wave-uniform base + lane*16.
__device__ __forceinline__ void gload16(const unsigned short* g, unsigned short* l) {
    __builtin_amdgcn_global_load_lds(
        (const __attribute__((address_space(1))) unsigned int*)g,
        (__attribute__((address_space(3))) unsigned int*)l, 16, 0, 0);
}

// ---------------------------------------------------------------------------
// Path A (bf16 workspace): prep (convert+norms), gram2 (global_load_lds MFMA),
// secret2 (coalesced LDS-staged batched gram).
// ---------------------------------------------------------------------------

// Convert fp32 -> bf16 workspace and compute bf16-rounded row norms.
// rows [0,32768): outputs; rows [32768,33792): encode. One wave per row.
__global__ void prep_k(const float* __restrict__ outp, const float* __restrict__ enc,
                       unsigned short* __restrict__ Xb, unsigned short* __restrict__ Eb,
                       float* __restrict__ sq_out, float* __restrict__ sq_enc) {
    int wid = threadIdx.x >> 6, l = threadIdx.x & 63;
    int r = blockIdx.x * 4 + wid;
    bool isOut = r < N_SEC * BDIM;
    const float* src = isOut ? (outp + (size_t)r * DDIM)
                             : (enc + (size_t)(r - N_SEC * BDIM) * DDIM);
    unsigned short* dst = isOut ? (Xb + (size_t)r * DDIM)
                                : (Eb + (size_t)(r - N_SEC * BDIM) * DDIM);
    const float4* s4 = (const float4*)src;
    float s = 0.f;
    #pragma unroll
    for (int h = 0; h < 2; ++h) {
        int c = l + h * 64;                    // 16B-chunk index 0..127
        float4 v0 = s4[2 * c], v1 = s4[2 * c + 1];
        i32x4 p = pack8(v0, v1);
        *(i32x4*)&dst[c * 8] = p;
        #pragma unroll
        for (int e = 0; e < 4; ++e) {
            unsigned u = (unsigned)p[e];
            float a = __uint_as_float(u << 16);
            float b = __uint_as_float(u & 0xFFFF0000u);
            s += a * a + b * b;
        }
    }
    s = wave_sum(s);
    if (l == 0) { if (isOut) sq_out[r] = s; else sq_enc[r - N_SEC * BDIM] = s; }
}

// m97-style gram: 128x128 tile, 4 waves 2x2, BK=32, global_load_lds width 16.
// LDS holds global chunk (row, c ^ ((row>>1)&3)) at (row, c) via pre-swizzled
// SOURCE address (m173); ds_read applies the same XOR -> ~2 lanes/bank (free).
// MODE 0: write d_sent. MODE 1: accumulate 2*(d_out-d_sent)^2 over upper tiles.
template<int MODE>
__global__ void gram2_k(const unsigned short* __restrict__ Xb, const float* __restrict__ sqv,
                        const float* __restrict__ dsent_r, float* __restrict__ dsent_w,
                        float* __restrict__ accum) {
    int idx = blockIdx.x, ti = 0;
    while (idx >= 8 - ti) { idx -= 8 - ti; ti++; }
    int tj = ti + idx;
    int n = (MODE == 1) ? blockIdx.y : 0;
    const unsigned short* Xn = Xb + (size_t)n * BDIM * DDIM;
    const float* sqn = sqv + n * BDIM;
    int i0 = ti * 128, j0 = tj * 128;
    bool diag = (ti == tj);

    __shared__ __align__(16) unsigned short Ash[128 * 32];
    __shared__ __align__(16) unsigned short Bsh[128 * 32];

    int t = threadIdx.x, wid = t >> 6, l = t & 63;
    int wr = wid >> 1, wc = wid & 1;
    bool dead = diag && (wr > wc);
    int cg = l >> 4, lr = l & 15;

    f32x4 acc[4][4];
    #pragma unroll
    for (int a = 0; a < 4; a++)
        #pragma unroll
        for (int c = 0; c < 4; c++) acc[a][c] = f32x4{0.f, 0.f, 0.f, 0.f};

    // staging: instr covers 16 rows/wave; lane l -> row rs, LDS chunk l&3,
    // global chunk (l&3) ^ ((rs>>1)&3)   [same swizzle bits for rs+64]
    int rs = wid * 16 + (l >> 2);
    int cgs = (l & 3) ^ ((rs >> 1) & 3);
    const unsigned short* gA0 = Xn + (size_t)(i0 + rs) * DDIM + cgs * 8;
    const unsigned short* gA1 = gA0 + (size_t)64 * DDIM;
    const unsigned short* gB0 = Xn + (size_t)(j0 + rs) * DDIM + cgs * 8;
    const unsigned short* gB1 = gB0 + (size_t)64 * DDIM;
    unsigned short* lA0 = &Ash[wid * 512];          // rows wid*16..+16
    unsigned short* lA1 = &Ash[2048 + wid * 512];   // rows 64+wid*16..
    unsigned short* lB0 = &Bsh[wid * 512];
    unsigned short* lB1 = &Bsh[2048 + wid * 512];

    for (int kt = 0; kt < DDIM / 32; ++kt) {
        int ko = kt * 32;
        __syncthreads();                 // previous reads done before overwrite
        gload16(gA0 + ko, lA0);
        gload16(gA1 + ko, lA1);
        gload16(gB0 + ko, lB0);
        gload16(gB1 + ko, lB1);
        __syncthreads();                 // vmcnt(0) drain -> tiles ready
        if (!dead) {
            bf16x8 af[4], bfr[4];
            #pragma unroll
            for (int f = 0; f < 4; f++) {
                int ra = wr * 64 + f * 16 + lr;
                af[f] = *(const bf16x8*)&Ash[ra * 32 + ((cg ^ ((ra >> 1) & 3)) * 8)];
                int rb = wc * 64 + f * 16 + lr;
                bfr[f] = *(const bf16x8*)&Bsh[rb * 32 + ((cg ^ ((rb >> 1) & 3)) * 8)];
            }
            #pragma unroll
            for (int fi = 0; fi < 4; fi++)
                #pragma unroll
                for (int fj = 0; fj < 4; fj++) {
                    if (diag && wr == wc && fj < fi) continue;
                    acc[fi][fj] = mfma16(af[fi], bfr[fj], acc[fi][fj]);
                }
        }
    }

    if (!dead) {
        float lsum = 0.f;
        #pragma unroll
        for (int fi = 0; fi < 4; fi++) {
            #pragma unroll
            for (int fj = 0; fj < 4; fj++) {
                if (diag && wr == wc && fj < fi) continue;
                int jg = j0 + wc * 64 + fj * 16 + lr;
                #pragma unroll
                for (int e = 0; e < 4; e++) {
                    int ig = i0 + wr * 64 + fi * 16 + cg * 4 + e;
                    float g = acc[fi][fj][e];
                    float d2 = sqn[ig] + sqn[jg] - 2.f * g;
                    float d = sqrtf(fmaxf(d2, 0.f) + 1e-12f);
                    if (MODE == 0) {
                        dsent_w[(size_t)ig * BDIM + jg] = d;
                    } else {
                        if (!diag || jg > ig) {
                            float diff = d - dsent_r[(size_t)ig * BDIM + jg];
                            lsum += diff * diff;
                        }
                    }
                }
            }
        }
        if (MODE == 1) {
            lsum = wave_sum(lsum * 2.f);
            if (l == 0) atomicAdd(accum, lsum);
        }
    }
}

// Batched per-b 32x32 gram from bf16 copy. Block: 4 b's (one per wave),
// D tiled by 128. Coalesced global_load_lds staging; XOR-swizzled chunks.
__global__ void secret2_k(const unsigned short* __restrict__ Xb,
                          const float* __restrict__ sq_out, float* __restrict__ accum) {
    __shared__ __align__(16) unsigned short S[32 * 4 * 128];   // [n][b][d] 32KB
    int t = threadIdx.x, wid = t >> 6, l = t & 63;
    int b0 = blockIdx.x * 4;
    int cg = l >> 4, lr = l & 15;
    f32x4 a00 = {0.f,0.f,0.f,0.f}, a01 = {0.f,0.f,0.f,0.f}, a11 = {0.f,0.f,0.f,0.f};

    for (int kt = 0; kt < 8; ++kt) {
        __syncthreads();
        #pragma unroll
        for (int m = 0; m < 8; ++m) {
            int n = m * 4 + wid;                 // wave-uniform
            // lane: b=cg, chunk c=lr, source chunk lr^(n&7)
            gload16(Xb + ((size_t)(n * BDIM + b0 + cg)) * DDIM + kt * 128 + ((lr ^ (n & 7)) * 8),
                    &S[n * 512]);
        }
        __syncthreads();
        #pragma unroll
        for (int k2 = 0; k2 < 4; ++k2) {
            int cs = k2 * 4 + cg;
            int cl = (cs ^ (lr & 7)) * 8;        // (16+lr)&7 == lr&7
            bf16x8 u0 = *(const bf16x8*)&S[lr * 512 + wid * 128 + cl];
            bf16x8 u1 = *(const bf16x8*)&S[(16 + lr) * 512 + wid * 128 + cl];
            a00 = mfma16(u0, u0, a00);
            a01 = mfma16(u0, u1, a01);
            a11 = mfma16(u1, u1, a11);
        }
    }

    float lsum = 0.f;
    int b = b0 + wid;
    auto proc = [&](const f32x4& acc, int rb, int cb) {
        #pragma unroll
        for (int e = 0; e < 4; e++) {
            int i = rb * 16 + cg * 4 + e;
            int j = cb * 16 + lr;
            if (j > i) {
                float d2 = sq_out[(size_t)i * BDIM + b] + sq_out[(size_t)j * BDIM + b] - 2.f * acc[e];
                float d = sqrtf(fmaxf(d2, 0.f) + 1e-12f);
                lsum += fmaxf(1.f - d, 0.f);
            }
        }
    };
    proc(a00, 0, 0); proc(a01, 0, 1); proc(a11, 1, 1);
    lsum = wave_sum(lsum);
    if (l == 0) atomicAdd(accum, lsum);
}

// ---------------------------------------------------------------------------
// Path B (fallback, round-0 known-good): fp32 reads + in-loop convert.
// ---------------------------------------------------------------------------

__global__ void norms_k(const float* __restrict__ outp, const float* __restrict__ enc,
                        float* __restrict__ sq_out, float* __restrict__ sq_enc) {
    int wid = threadIdx.x >> 6, l = threadIdx.x & 63;
    int r = blockIdx.x * 4 + wid;
    const float* src = (r < N_SEC * BDIM) ? (outp + (size_t)r * DDIM)
                                          : (enc + (size_t)(r - N_SEC * BDIM) * DDIM);
    float s = 0.f;
    #pragma unroll
    for (int q = 0; q < 4; q++) {
        float4 v = reinterpret_cast<const float4*>(src)[l + q * 64];
        unsigned u0 = pk2(v.x, v.y), u1 = pk2(v.z, v.w);
        float a = __uint_as_float(u0 << 16), b = __uint_as_float(u0 & 0xFFFF0000u);
        float c = __uint_as_float(u1 << 16), d = __uint_as_float(u1 & 0xFFFF0000u);
        s += a * a + b * b + c * c + d * d;
    }
    s = wave_sum(s);
    if (l == 0) { if (r < N_SEC * BDIM) sq_out[r] = s; else sq_enc[r - N_SEC * BDIM] = s; }
}

template<int MODE>
__global__ void gram_k(const float* __restrict__ X, const float* __restrict__ sqv,
                       const float* __restrict__ dsent_r, float* __restrict__ dsent_w,
                       float* __restrict__ accum) {
    int idx = blockIdx.x, ti = 0;
    while (idx >= 8 - ti) { idx -= 8 - ti; ti++; }
    int tj = ti + idx;
    int n = (MODE == 1) ? blockIdx.y : 0;
    const float* Xn = X + (size_t)n * BDIM * DDIM;
    const float* sqn = sqv + n * BDIM;
    int i0 = ti * 128, j0 = tj * 128;
    bool diag = (ti == tj);
    __shared__ __align__(16) unsigned short Ash[128 * 32];
    __shared__ __align__(16) unsigned short Bsh[128 * 32];
    int t = threadIdx.x, wid = t >> 6, l = t & 63;
    int wr = wid >> 1, wc = wid & 1;
    bool dead = diag && (wr > wc);
    int cg = l >> 4, lr = l & 15;
    f32x4 acc[4][4];
    #pragma unroll
    for (int a = 0; a < 4; a++)
        #pragma unroll
        for (int c = 0; c < 4; c++) acc[a][c] = f32x4{0.f, 0.f, 0.f, 0.f};
    int r0 = t >> 2, c0 = t & 3;
    int swz0 = (c0 ^ (r0 & 3)) * 8;
    int off0 = r0 * 32 + swz0;
    int off1 = (r0 + 64) * 32 + swz0;
    for (int kt = 0; kt < DDIM / 32; ++kt) {
        int k0 = kt * 32;
        const float4* pa0 = (const float4*)(Xn + (size_t)(i0 + r0) * DDIM + k0 + c0 * 8);
        const float4* pa1 = (const float4*)(Xn + (size_t)(i0 + r0 + 64) * DDIM + k0 + c0 * 8);
        const float4* pb0 = (const float4*)(Xn + (size_t)(j0 + r0) * DDIM + k0 + c0 * 8);
        const float4* pb1 = (const float4*)(Xn + (size_t)(j0 + r0 + 64) * DDIM + k0 + c0 * 8);
        float4 a00 = pa0[0], a01 = pa0[1];
        float4 a10 = pa1[0], a11 = pa1[1];
        float4 b00 = pb0[0], b01 = pb0[1];
        float4 b10 = pb1[0], b11 = pb1[1];
        __syncthreads();
        *(i32x4*)&Ash[off0] = pack8(a00, a01);
        *(i32x4*)&Ash[off1] = pack8(a10, a11);
        *(i32x4*)&Bsh[off0] = pack8(b00, b01);
        *(i32x4*)&Bsh[off1] = pack8(b10, b11);
        __syncthreads();
        if (!dead) {
            bf16x8 af[4], bfr[4];
            #pragma unroll
            for (int f = 0; f < 4; f++) {
                int ra = wr * 64 + f * 16 + lr;
                af[f] = *(const bf16x8*)&Ash[ra * 32 + ((cg ^ (ra & 3)) * 8)];
                int rb = wc * 64 + f * 16 + lr;
                bfr[f] = *(const bf16x8*)&Bsh[rb * 32 + ((cg ^ (rb & 3)) * 8)];
            }
            #pragma unroll
            for (int fi = 0; fi < 4; fi++)
                #pragma unroll
                for (int fj = 0; fj < 4; fj++) {
                    if (diag && wr == wc && fj < fi) continue;
                    acc[fi][fj] = mfma16(af[fi], bfr[fj], acc[fi][fj]);
                }
        }
    }
    if (!dead) {
        float lsum = 0.f;
        #pragma unroll
        for (int fi = 0; fi < 4; fi++) {
            #pragma unroll
            for (int fj = 0; fj < 4; fj++) {
                if (diag && wr == wc && fj < fi) continue;
                int jg = j0 + wc * 64 + fj * 16 + lr;
                #pragma unroll
                for (int e = 0; e < 4; e++) {
                    int ig = i0 + wr * 64 + fi * 16 + cg * 4 + e;
                    float g = acc[fi][fj][e];
                    float d2 = sqn[ig] + sqn[jg] - 2.f * g;
                    float d = sqrtf(fmaxf(d2, 0.f) + 1e-12f);
                    if (MODE == 0) {
                        dsent_w[(size_t)ig * BDIM + jg] = d;
                    } else {
                        if (!diag || jg > ig) {
                            float diff = d - dsent_r[(size_t)ig * BDIM + jg];
                            lsum += diff * diff;
                        }
                    }
                }
            }
        }
        if (MODE == 1) {
            lsum = wave_sum(lsum * 2.f);
            if (l == 0) atomicAdd(accum, lsum);
        }
    }
}

__global__ void secret_k(const float* __restrict__ X, const float* __restrict__ sq_out,
                         float* __restrict__ accum) {
    int wid = threadIdx.x >> 6, l = threadIdx.x & 63;
    int b = blockIdx.x * 4 + wid;
    int cg = l >> 4, lr = l & 15;
    f32x4 a00 = {0.f,0.f,0.f,0.f}, a01 = {0.f,0.f,0.f,0.f}, a11 = {0.f,0.f,0.f,0.f};
    for (int kt = 0; kt < 32; ++kt) {
        int k0 = kt * 32 + cg * 8;
        const float4* p0 = (const float4*)(X + ((size_t)lr * BDIM + b) * DDIM + k0);
        const float4* p1 = (const float4*)(X + ((size_t)(16 + lr) * BDIM + b) * DDIM + k0);
        union { i32x4 i; bf16x8 s; } u0, u1;
        u0.i = pack8(p0[0], p0[1]);
        u1.i = pack8(p1[0], p1[1]);
        a00 = mfma16(u0.s, u0.s, a00);
        a01 = mfma16(u0.s, u1.s, a01);
        a11 = mfma16(u1.s, u1.s, a11);
    }
    float lsum = 0.f;
    auto proc = [&](const f32x4& acc, int rb, int cb) {
        #pragma unroll
        for (int e = 0; e < 4; e++) {
            int i = rb * 16 + cg * 4 + e;
            int j = cb * 16 + lr;
            if (j > i) {
                float d2 = sq_out[(size_t)i * BDIM + b] + sq_out[(size_t)j * BDIM + b] - 2.f * acc[e];
                float d = sqrtf(fmaxf(d2, 0.f) + 1e-12f);
                lsum += fmaxf(1.f - d, 0.f);
            }
        }
    };
    proc(a00, 0, 0); proc(a01, 0, 1); proc(a11, 1, 1);
    lsum = wave_sum(lsum);
    if (l == 0) atomicAdd(accum, lsum);
}

__global__ void init_k(float* sums) { sums[threadIdx.x] = 0.f; }

__global__ void fin_k(const float* __restrict__ sums, float* __restrict__ out) {
    float sl = sums[0] * (1.0f / 33554432.0f);            // / (N*B*B)
    float sec = sums[1] * (1.0f / (1024.0f * 496.0f));    // / B / n_pairs
    out[0] = 0.5f * sl + 0.5f * sec;
    out[1] = sl;
    out[2] = sec;
}

extern "C" void kernel_launch(void* const* d_in, const int* in_sizes, int n_in,
                              void* d_out, int out_size, void* d_ws, size_t ws_size,
                              hipStream_t stream) {
    const float* outputs = (const float*)d_in[0];   // [32,1024,1024] f32
    const float* enc     = (const float*)d_in[1];   // [1024,1024] f32
    float* out = (float*)d_out;                     // 3 floats

    // ws layout: sums[64] | sq_out[32768] | sq_enc[1024] | dsent[1M] f32
    //            | Xbf [32*1024*1024] bf16 | Ebf [1024*1024] bf16
    float* sums   = (float*)d_ws;
    float* sq_out = sums + 64;
    float* sq_enc = sq_out + N_SEC * BDIM;
    float* dsent  = sq_enc + BDIM;
    unsigned short* Xbf = (unsigned short*)(dsent + (size_t)BDIM * BDIM);
    unsigned short* Ebf = Xbf + (size_t)N_SEC * BDIM * DDIM;

    const size_t NEED = 256 + 131072 + 4096 + 4194304
                      + (size_t)N_SEC * BDIM * DDIM * 2 + (size_t)BDIM * DDIM * 2;

    hipLaunchKernelGGL(init_k, dim3(1), dim3(2), 0, stream, sums);

    if (ws_size >= NEED) {
        hipLaunchKernelGGL(prep_k, dim3((N_SEC * BDIM + BDIM) / 4), dim3(256), 0, stream,
                           outputs, enc, Xbf, Ebf, sq_out, sq_enc);
        hipLaunchKernelGGL((gram2_k<0>), dim3(36), dim3(256), 0, stream,
                           Ebf, sq_enc, (const float*)nullptr, dsent, (float*)nullptr);
        hipLaunchKernelGGL((gram2_k<1>), dim3(36, N_SEC), dim3(256), 0, stream,
                           Xbf, sq_out, (const float*)dsent, (float*)nullptr, &sums[0]);
        hipLaunchKernelGGL(secret2_k, dim3(BDIM / 4), dim3(256), 0, stream,
                           Xbf, sq_out, &sums[1]);
    } else {
        hipLaunchKernelGGL(norms_k, dim3((N_SEC * BDIM + BDIM) / 4), dim3(256), 0, stream,
                           outputs, enc, sq_out, sq_enc);
        hipLaunchKernelGGL((gram_k<0>), dim3(36), dim3(256), 0, stream,
                           enc, sq_enc, (const float*)nullptr, dsent, (float*)nullptr);
        hipLaunchKernelGGL((gram_k<1>), dim3(36, N_SEC), dim3(256), 0, stream,
                           outputs, sq_out, (const float*)dsent, (float*)nullptr, &sums[0]);
        hipLaunchKernelGGL(secret_k, dim3(BDIM / 4), dim3(256), 0, stream,
                           outputs, sq_out, &sums[1]);
    }
    hipLaunchKernelGGL(fin_k, dim3(1), dim3(1), 0, stream, sums, out);
}

// Round 3
// 198.839 us; speedup vs baseline: 1.4614x; 1.1888x over previous
//
#include <hip/hip_runtime.h>
#include <hip/hip_bf16.h>

#define N_SEC 32
#define BDIM 1024
#define DDIM 1024

typedef __attribute__((ext_vector_type(8))) short bf16x8;
typedef __attribute__((ext_vector_type(4))) float f32x4;
typedef __attribute__((ext_vector_type(4))) int i32x4;

__device__ __forceinline__ unsigned pk2(float a, float b) {
    union { __hip_bfloat162 h; unsigned u; } cv;
    cv.h = __float22bfloat162_rn(make_float2(a, b));
    return cv.u;
}

__device__ __forceinline__ i32x4 pack8(float4 a, float4 b) {
    i32x4 r;
    r[0] = pk2(a.x, a.y); r[1] = pk2(a.z, a.w);
    r[2] = pk2(b.x, b.y); r[3] = pk2(b.z, b.w);
    return r;
}

__device__ __forceinline__ f32x4 mfma16(bf16x8 a, bf16x8 b, f32x4 c) {
    return __builtin_amdgcn_mfma_f32_16x16x32_bf16(a, b, c, 0, 0, 0);
}

__device__ __forceinline__ float wave_sum(float v) {
    #pragma unroll
    for (int off = 32; off > 0; off >>= 1) v += __shfl_down(v, off, 64);
    return v;
}

// async global->LDS, 16B per lane. LDS dest is wave-uniform base + lane*16.
__device__ __forceinline__ void gload16(const unsigned short* g, unsigned short* l) {
    __builtin_amdgcn_global_load_lds(
        (const __attribute__((address_space(1))) unsigned int*)g,
        (__attribute__((address_space(3))) unsigned int*)l, 16, 0, 0);
}

// ---------------------------------------------------------------------------
// Path A: prep (convert+norms), gram3 (2-phase dbuf global_load_lds MFMA),
// secret3 (2-phase dbuf batched gram).
// ---------------------------------------------------------------------------

__global__ void prep_k(const float* __restrict__ outp, const float* __restrict__ enc,
                       unsigned short* __restrict__ Xb, unsigned short* __restrict__ Eb,
                       float* __restrict__ sq_out, float* __restrict__ sq_enc) {
    int wid = threadIdx.x >> 6, l = threadIdx.x & 63;
    int r = blockIdx.x * 4 + wid;
    bool isOut = r < N_SEC * BDIM;
    const float* src = isOut ? (outp + (size_t)r * DDIM)
                             : (enc + (size_t)(r - N_SEC * BDIM) * DDIM);
    unsigned short* dst = isOut ? (Xb + (size_t)r * DDIM)
                                : (Eb + (size_t)(r - N_SEC * BDIM) * DDIM);
    const float4* s4 = (const float4*)src;
    float s = 0.f;
    #pragma unroll
    for (int h = 0; h < 2; ++h) {
        int c = l + h * 64;
        float4 v0 = s4[2 * c], v1 = s4[2 * c + 1];
        i32x4 p = pack8(v0, v1);
        *(i32x4*)&dst[c * 8] = p;
        #pragma unroll
        for (int e = 0; e < 4; ++e) {
            unsigned u = (unsigned)p[e];
            float a = __uint_as_float(u << 16);
            float b = __uint_as_float(u & 0xFFFF0000u);
            s += a * a + b * b;
        }
    }
    s = wave_sum(s);
    if (l == 0) { if (isOut) sq_out[r] = s; else sq_enc[r - N_SEC * BDIM] = s; }
}

// 128x128 tile, 4 waves 2x2, BK=32, global_load_lds w16, 2-phase double-buffer
// (T3 minimal recipe: stage t+1 BEFORE compute t, one barrier per K-step).
// XOR chunk swizzle via pre-swizzled global source (m173).
// MODE 1 grid is 1-D 1152 with XCD-aware decode: xcd=g&7 owns 4 n-slices.
template<int MODE>
__global__ void gram3_k(const unsigned short* __restrict__ Xb, const float* __restrict__ sqv,
                        const float* __restrict__ dsent_r, float* __restrict__ dsent_w,
                        float* __restrict__ accum) {
    int n, tile;
    if (MODE == 1) {
        int g = blockIdx.x;           // 0..1151
        int xcd = g & 7, local = g >> 3;
        n = xcd * 4 + local / 36;     // 4 consecutive n per XCD -> L2 locality
        tile = local % 36;
    } else { n = 0; tile = blockIdx.x; }
    int idx = tile, ti = 0;
    while (idx >= 8 - ti) { idx -= 8 - ti; ti++; }
    int tj = ti + idx;
    const unsigned short* Xn = Xb + (size_t)n * BDIM * DDIM;
    const float* sqn = sqv + n * BDIM;
    int i0 = ti * 128, j0 = tj * 128;
    bool diag = (ti == tj);

    __shared__ __align__(16) unsigned short Ash[2][4096];
    __shared__ __align__(16) unsigned short Bsh[2][4096];

    int t = threadIdx.x, wid = t >> 6, l = t & 63;
    int wr = wid >> 1, wc = wid & 1;
    bool dead = diag && (wr > wc);
    int cg = l >> 4, lr = l & 15;

    f32x4 acc[4][4];
    #pragma unroll
    for (int a = 0; a < 4; a++)
        #pragma unroll
        for (int c = 0; c < 4; c++) acc[a][c] = f32x4{0.f, 0.f, 0.f, 0.f};

    // staging addresses: lane l -> row rs, LDS chunk l&3, global chunk pre-swizzled
    int rs = wid * 16 + (l >> 2);
    int cgs = (l & 3) ^ ((rs >> 1) & 3);
    const unsigned short* gA0 = Xn + (size_t)(i0 + rs) * DDIM + cgs * 8;
    const unsigned short* gA1 = gA0 + (size_t)64 * DDIM;
    const unsigned short* gB0 = Xn + (size_t)(j0 + rs) * DDIM + cgs * 8;
    const unsigned short* gB1 = gB0 + (size_t)64 * DDIM;

    auto stage = [&](int buf, int kt) {
        int ko = kt * 32;
        gload16(gA0 + ko, &Ash[buf][wid * 512]);
        gload16(gA1 + ko, &Ash[buf][2048 + wid * 512]);
        gload16(gB0 + ko, &Bsh[buf][wid * 512]);
        gload16(gB1 + ko, &Bsh[buf][2048 + wid * 512]);
    };
    auto compute = [&](int buf) {
        if (dead) return;
        bf16x8 af[4], bfr[4];
        #pragma unroll
        for (int f = 0; f < 4; f++) {
            int ra = wr * 64 + f * 16 + lr;
            af[f] = *(const bf16x8*)&Ash[buf][ra * 32 + ((cg ^ ((ra >> 1) & 3)) * 8)];
            int rb = wc * 64 + f * 16 + lr;
            bfr[f] = *(const bf16x8*)&Bsh[buf][rb * 32 + ((cg ^ ((rb >> 1) & 3)) * 8)];
        }
        #pragma unroll
        for (int fi = 0; fi < 4; fi++)
            #pragma unroll
            for (int fj = 0; fj < 4; fj++) {
                if (diag && wr == wc && fj < fi) continue;
                acc[fi][fj] = mfma16(af[fi], bfr[fj], acc[fi][fj]);
            }
    };

    // 2-phase pipeline, buffer index compile-time via manual x2 unroll.
    stage(0, 0);
    __syncthreads();
    for (int kt = 0; kt < 30; kt += 2) {
        stage(1, kt + 1);
        compute(0);
        __syncthreads();
        stage(0, kt + 2);
        compute(1);
        __syncthreads();
    }
    stage(1, 31);
    compute(0);
    __syncthreads();
    compute(1);

    if (!dead) {
        float lsum = 0.f;
        #pragma unroll
        for (int fi = 0; fi < 4; fi++) {
            #pragma unroll
            for (int fj = 0; fj < 4; fj++) {
                if (diag && wr == wc && fj < fi) continue;
                int jg = j0 + wc * 64 + fj * 16 + lr;
                #pragma unroll
                for (int e = 0; e < 4; e++) {
                    int ig = i0 + wr * 64 + fi * 16 + cg * 4 + e;
                    float g = acc[fi][fj][e];
                    float d2 = sqn[ig] + sqn[jg] - 2.f * g;
                    float d = sqrtf(fmaxf(d2, 0.f) + 1e-12f);
                    if (MODE == 0) {
                        dsent_w[(size_t)ig * BDIM + jg] = d;
                    } else {
                        if (!diag || jg > ig) {
                            float diff = d - dsent_r[(size_t)ig * BDIM + jg];
                            lsum += diff * diff;
                        }
                    }
                }
            }
        }
        if (MODE == 1) {
            lsum = wave_sum(lsum * 2.f);
            if (l == 0) atomicAdd(accum, lsum);
        }
    }
}

// Batched per-b 32x32 gram, 2-phase double-buffered staging.
__global__ void secret3_k(const unsigned short* __restrict__ Xb,
                          const float* __restrict__ sq_out, float* __restrict__ accum) {
    __shared__ __align__(16) unsigned short S[2][32 * 4 * 128];   // 2 x 32KB
    int t = threadIdx.x, wid = t >> 6, l = t & 63;
    int b0 = blockIdx.x * 4;
    int cg = l >> 4, lr = l & 15;
    f32x4 a00 = {0.f,0.f,0.f,0.f}, a01 = {0.f,0.f,0.f,0.f}, a11 = {0.f,0.f,0.f,0.f};

    auto stage = [&](int buf, int kt) {
        #pragma unroll
        for (int m = 0; m < 8; ++m) {
            int n = m * 4 + wid;
            gload16(Xb + ((size_t)(n * BDIM + b0 + cg)) * DDIM + kt * 128 + ((lr ^ (n & 7)) * 8),
                    &S[buf][n * 512]);
        }
    };
    auto compute = [&](int buf) {
        #pragma unroll
        for (int k2 = 0; k2 < 4; ++k2) {
            int cs = k2 * 4 + cg;
            int cl = (cs ^ (lr & 7)) * 8;
            bf16x8 u0 = *(const bf16x8*)&S[buf][lr * 512 + wid * 128 + cl];
            bf16x8 u1 = *(const bf16x8*)&S[buf][(16 + lr) * 512 + wid * 128 + cl];
            a00 = mfma16(u0, u0, a00);
            a01 = mfma16(u0, u1, a01);
            a11 = mfma16(u1, u1, a11);
        }
    };

    stage(0, 0);
    __syncthreads();
    for (int kt = 0; kt < 6; kt += 2) {
        stage(1, kt + 1);
        compute(0);
        __syncthreads();
        stage(0, kt + 2);
        compute(1);
        __syncthreads();
    }
    stage(1, 7);
    compute(0);
    __syncthreads();
    compute(1);

    float lsum = 0.f;
    int b = b0 + wid;
    auto proc = [&](const f32x4& acc, int rb, int cb) {
        #pragma unroll
        for (int e = 0; e < 4; e++) {
            int i = rb * 16 + cg * 4 + e;
            int j = cb * 16 + lr;
            if (j > i) {
                float d2 = sq_out[(size_t)i * BDIM + b] + sq_out[(size_t)j * BDIM + b] - 2.f * acc[e];
                float d = sqrtf(fmaxf(d2, 0.f) + 1e-12f);
                lsum += fmaxf(1.f - d, 0.f);
            }
        }
    };
    proc(a00, 0, 0); proc(a01, 0, 1); proc(a11, 1, 1);
    lsum = wave_sum(lsum);
    if (l == 0) atomicAdd(accum, lsum);
}

// ---------------------------------------------------------------------------
// Path B (fallback, round-0 known-good): fp32 reads + in-loop convert.
// ---------------------------------------------------------------------------

__global__ void norms_k(const float* __restrict__ outp, const float* __restrict__ enc,
                        float* __restrict__ sq_out, float* __restrict__ sq_enc) {
    int wid = threadIdx.x >> 6, l = threadIdx.x & 63;
    int r = blockIdx.x * 4 + wid;
    const float* src = (r < N_SEC * BDIM) ? (outp + (size_t)r * DDIM)
                                          : (enc + (size_t)(r - N_SEC * BDIM) * DDIM);
    float s = 0.f;
    #pragma unroll
    for (int q = 0; q < 4; q++) {
        float4 v = reinterpret_cast<const float4*>(src)[l + q * 64];
        unsigned u0 = pk2(v.x, v.y), u1 = pk2(v.z, v.w);
        float a = __uint_as_float(u0 << 16), b = __uint_as_float(u0 & 0xFFFF0000u);
        float c = __uint_as_float(u1 << 16), d = __uint_as_float(u1 & 0xFFFF0000u);
        s += a * a + b * b + c * c + d * d;
    }
    s = wave_sum(s);
    if (l == 0) { if (r < N_SEC * BDIM) sq_out[r] = s; else sq_enc[r - N_SEC * BDIM] = s; }
}

template<int MODE>
__global__ void gram_k(const float* __restrict__ X, const float* __restrict__ sqv,
                       const float* __restrict__ dsent_r, float* __restrict__ dsent_w,
                       float* __restrict__ accum) {
    int idx = blockIdx.x, ti = 0;
    while (idx >= 8 - ti) { idx -= 8 - ti; ti++; }
    int tj = ti + idx;
    int n = (MODE == 1) ? blockIdx.y : 0;
    const float* Xn = X + (size_t)n * BDIM * DDIM;
    const float* sqn = sqv + n * BDIM;
    int i0 = ti * 128, j0 = tj * 128;
    bool diag = (ti == tj);
    __shared__ __align__(16) unsigned short Ash[128 * 32];
    __shared__ __align__(16) unsigned short Bsh[128 * 32];
    int t = threadIdx.x, wid = t >> 6, l = t & 63;
    int wr = wid >> 1, wc = wid & 1;
    bool dead = diag && (wr > wc);
    int cg = l >> 4, lr = l & 15;
    f32x4 acc[4][4];
    #pragma unroll
    for (int a = 0; a < 4; a++)
        #pragma unroll
        for (int c = 0; c < 4; c++) acc[a][c] = f32x4{0.f, 0.f, 0.f, 0.f};
    int r0 = t >> 2, c0 = t & 3;
    int swz0 = (c0 ^ (r0 & 3)) * 8;
    int off0 = r0 * 32 + swz0;
    int off1 = (r0 + 64) * 32 + swz0;
    for (int kt = 0; kt < DDIM / 32; ++kt) {
        int k0 = kt * 32;
        const float4* pa0 = (const float4*)(Xn + (size_t)(i0 + r0) * DDIM + k0 + c0 * 8);
        const float4* pa1 = (const float4*)(Xn + (size_t)(i0 + r0 + 64) * DDIM + k0 + c0 * 8);
        const float4* pb0 = (const float4*)(Xn + (size_t)(j0 + r0) * DDIM + k0 + c0 * 8);
        const float4* pb1 = (const float4*)(Xn + (size_t)(j0 + r0 + 64) * DDIM + k0 + c0 * 8);
        float4 a00 = pa0[0], a01 = pa0[1];
        float4 a10 = pa1[0], a11 = pa1[1];
        float4 b00 = pb0[0], b01 = pb0[1];
        float4 b10 = pb1[0], b11 = pb1[1];
        __syncthreads();
        *(i32x4*)&Ash[off0] = pack8(a00, a01);
        *(i32x4*)&Ash[off1] = pack8(a10, a11);
        *(i32x4*)&Bsh[off0] = pack8(b00, b01);
        *(i32x4*)&Bsh[off1] = pack8(b10, b11);
        __syncthreads();
        if (!dead) {
            bf16x8 af[4], bfr[4];
            #pragma unroll
            for (int f = 0; f < 4; f++) {
                int ra = wr * 64 + f * 16 + lr;
                af[f] = *(const bf16x8*)&Ash[ra * 32 + ((cg ^ (ra & 3)) * 8)];
                int rb = wc * 64 + f * 16 + lr;
                bfr[f] = *(const bf16x8*)&Bsh[rb * 32 + ((cg ^ (rb & 3)) * 8)];
            }
            #pragma unroll
            for (int fi = 0; fi < 4; fi++)
                #pragma unroll
                for (int fj = 0; fj < 4; fj++) {
                    if (diag && wr == wc && fj < fi) continue;
                    acc[fi][fj] = mfma16(af[fi], bfr[fj], acc[fi][fj]);
                }
        }
    }
    if (!dead) {
        float lsum = 0.f;
        #pragma unroll
        for (int fi = 0; fi < 4; fi++) {
            #pragma unroll
            for (int fj = 0; fj < 4; fj++) {
                if (diag && wr == wc && fj < fi) continue;
                int jg = j0 + wc * 64 + fj * 16 + lr;
                #pragma unroll
                for (int e = 0; e < 4; e++) {
                    int ig = i0 + wr * 64 + fi * 16 + cg * 4 + e;
                    float g = acc[fi][fj][e];
                    float d2 = sqn[ig] + sqn[jg] - 2.f * g;
                    float d = sqrtf(fmaxf(d2, 0.f) + 1e-12f);
                    if (MODE == 0) {
                        dsent_w[(size_t)ig * BDIM + jg] = d;
                    } else {
                        if (!diag || jg > ig) {
                            float diff = d - dsent_r[(size_t)ig * BDIM + jg];
                            lsum += diff * diff;
                        }
                    }
                }
            }
        }
        if (MODE == 1) {
            lsum = wave_sum(lsum * 2.f);
            if (l == 0) atomicAdd(accum, lsum);
        }
    }
}

__global__ void secret_k(const float* __restrict__ X, const float* __restrict__ sq_out,
                         float* __restrict__ accum) {
    int wid = threadIdx.x >> 6, l = threadIdx.x & 63;
    int b = blockIdx.x * 4 + wid;
    int cg = l >> 4, lr = l & 15;
    f32x4 a00 = {0.f,0.f,0.f,0.f}, a01 = {0.f,0.f,0.f,0.f}, a11 = {0.f,0.f,0.f,0.f};
    for (int kt = 0; kt < 32; ++kt) {
        int k0 = kt * 32 + cg * 8;
        const float4* p0 = (const float4*)(X + ((size_t)lr * BDIM + b) * DDIM + k0);
        const float4* p1 = (const float4*)(X + ((size_t)(16 + lr) * BDIM + b) * DDIM + k0);
        union { i32x4 i; bf16x8 s; } u0, u1;
        u0.i = pack8(p0[0], p0[1]);
        u1.i = pack8(p1[0], p1[1]);
        a00 = mfma16(u0.s, u0.s, a00);
        a01 = mfma16(u0.s, u1.s, a01);
        a11 = mfma16(u1.s, u1.s, a11);
    }
    float lsum = 0.f;
    auto proc = [&](const f32x4& acc, int rb, int cb) {
        #pragma unroll
        for (int e = 0; e < 4; e++) {
            int i = rb * 16 + cg * 4 + e;
            int j = cb * 16 + lr;
            if (j > i) {
                float d2 = sq_out[(size_t)i * BDIM + b] + sq_out[(size_t)j * BDIM + b] - 2.f * acc[e];
                float d = sqrtf(fmaxf(d2, 0.f) + 1e-12f);
                lsum += fmaxf(1.f - d, 0.f);
            }
        }
    };
    proc(a00, 0, 0); proc(a01, 0, 1); proc(a11, 1, 1);
    lsum = wave_sum(lsum);
    if (l == 0) atomicAdd(accum, lsum);
}

__global__ void init_k(float* sums) { sums[threadIdx.x] = 0.f; }

__global__ void fin_k(const float* __restrict__ sums, float* __restrict__ out) {
    float sl = sums[0] * (1.0f / 33554432.0f);            // / (N*B*B)
    float sec = sums[1] * (1.0f / (1024.0f * 496.0f));    // / B / n_pairs
    out[0] = 0.5f * sl + 0.5f * sec;
    out[1] = sl;
    out[2] = sec;
}

extern "C" void kernel_launch(void* const* d_in, const int* in_sizes, int n_in,
                              void* d_out, int out_size, void* d_ws, size_t ws_size,
                              hipStream_t stream) {
    const float* outputs = (const float*)d_in[0];   // [32,1024,1024] f32
    const float* enc     = (const float*)d_in[1];   // [1024,1024] f32
    float* out = (float*)d_out;                     // 3 floats

    // ws layout: sums[64] | sq_out[32768] | sq_enc[1024] | dsent[1M] f32
    //            | Xbf [32*1024*1024] bf16 | Ebf [1024*1024] bf16
    float* sums   = (float*)d_ws;
    float* sq_out = sums + 64;
    float* sq_enc = sq_out + N_SEC * BDIM;
    float* dsent  = sq_enc + BDIM;
    unsigned short* Xbf = (unsigned short*)(dsent + (size_t)BDIM * BDIM);
    unsigned short* Ebf = Xbf + (size_t)N_SEC * BDIM * DDIM;

    const size_t NEED = 256 + 131072 + 4096 + 4194304
                      + (size_t)N_SEC * BDIM * DDIM * 2 + (size_t)BDIM * DDIM * 2;

    hipLaunchKernelGGL(init_k, dim3(1), dim3(2), 0, stream, sums);

    if (ws_size >= NEED) {
        hipLaunchKernelGGL(prep_k, dim3((N_SEC * BDIM + BDIM) / 4), dim3(256), 0, stream,
                           outputs, enc, Xbf, Ebf, sq_out, sq_enc);
        hipLaunchKernelGGL((gram3_k<0>), dim3(36), dim3(256), 0, stream,
                           Ebf, sq_enc, (const float*)nullptr, dsent, (float*)nullptr);
        hipLaunchKernelGGL((gram3_k<1>), dim3(36 * N_SEC), dim3(256), 0, stream,
                           Xbf, sq_out, (const float*)dsent, (float*)nullptr, &sums[0]);
        hipLaunchKernelGGL(secret3_k, dim3(BDIM / 4), dim3(256), 0, stream,
                           Xbf, sq_out, &sums[1]);
    } else {
        hipLaunchKernelGGL(norms_k, dim3((N_SEC * BDIM + BDIM) / 4), dim3(256), 0, stream,
                           outputs, enc, sq_out, sq_enc);
        hipLaunchKernelGGL((gram_k<0>), dim3(36), dim3(256), 0, stream,
                           enc, sq_enc, (const float*)nullptr, dsent, (float*)nullptr);
        hipLaunchKernelGGL((gram_k<1>), dim3(36, N_SEC), dim3(256), 0, stream,
                           outputs, sq_out, (const float*)dsent, (float*)nullptr, &sums[0]);
        hipLaunchKernelGGL(secret_k, dim3(BDIM / 4), dim3(256), 0, stream,
                           outputs, sq_out, &sums[1]);
    }
    hipLaunchKernelGGL(fin_k, dim3(1), dim3(1), 0, stream, sums, out);
}

// Round 4
// 173.432 us; speedup vs baseline: 1.6755x; 1.1465x over previous
//
#include <hip/hip_runtime.h>
#include <hip/hip_bf16.h>

#define N_SEC 32
#define BDIM 1024
#define DDIM 1024

typedef __attribute__((ext_vector_type(8))) short bf16x8;
typedef __attribute__((ext_vector_type(4))) float f32x4;
typedef __attribute__((ext_vector_type(4))) int i32x4;

#define WAITVM(n) asm volatile("s_waitcnt vmcnt(" #n ")" ::: "memory")

__device__ __forceinline__ void pipe_barrier() {
    __builtin_amdgcn_s_barrier();
    asm volatile("" ::: "memory");          // block IR-level load hoisting above barrier
    __builtin_amdgcn_sched_barrier(0);      // block MIR-level scheduling across
}

__device__ __forceinline__ unsigned pk2(float a, float b) {
    union { __hip_bfloat162 h; unsigned u; } cv;
    cv.h = __float22bfloat162_rn(make_float2(a, b));
    return cv.u;
}

__device__ __forceinline__ i32x4 pack8(float4 a, float4 b) {
    i32x4 r;
    r[0] = pk2(a.x, a.y); r[1] = pk2(a.z, a.w);
    r[2] = pk2(b.x, b.y); r[3] = pk2(b.z, b.w);
    return r;
}

__device__ __forceinline__ f32x4 mfma16(bf16x8 a, bf16x8 b, f32x4 c) {
    return __builtin_amdgcn_mfma_f32_16x16x32_bf16(a, b, c, 0, 0, 0);
}

__device__ __forceinline__ float wave_sum(float v) {
    #pragma unroll
    for (int off = 32; off > 0; off >>= 1) v += __shfl_down(v, off, 64);
    return v;
}

// async global->LDS, 16B per lane. LDS dest is wave-uniform base + lane*16.
__device__ __forceinline__ void gload16(const unsigned short* g, unsigned short* l) {
    __builtin_amdgcn_global_load_lds(
        (const __attribute__((address_space(1))) unsigned int*)g,
        (__attribute__((address_space(3))) unsigned int*)l, 16, 0, 0);
}

// ---------------------------------------------------------------------------
// Path A: prep (convert+norms), gram4 (4-buffer counted-vmcnt pipeline),
// secret4 (2-phase dbuf), fin2 (partials reduce). NO same-address atomics.
// ---------------------------------------------------------------------------

__global__ void prep_k(const float* __restrict__ outp, const float* __restrict__ enc,
                       unsigned short* __restrict__ Xb, unsigned short* __restrict__ Eb,
                       float* __restrict__ sq_out, float* __restrict__ sq_enc) {
    int wid = threadIdx.x >> 6, l = threadIdx.x & 63;
    int r = blockIdx.x * 4 + wid;
    bool isOut = r < N_SEC * BDIM;
    const float* src = isOut ? (outp + (size_t)r * DDIM)
                             : (enc + (size_t)(r - N_SEC * BDIM) * DDIM);
    unsigned short* dst = isOut ? (Xb + (size_t)r * DDIM)
                                : (Eb + (size_t)(r - N_SEC * BDIM) * DDIM);
    const float4* s4 = (const float4*)src;
    float s = 0.f;
    #pragma unroll
    for (int h = 0; h < 2; ++h) {
        int c = l + h * 64;
        float4 v0 = s4[2 * c], v1 = s4[2 * c + 1];
        i32x4 p = pack8(v0, v1);
        *(i32x4*)&dst[c * 8] = p;
        #pragma unroll
        for (int e = 0; e < 4; ++e) {
            unsigned u = (unsigned)p[e];
            float a = __uint_as_float(u << 16);
            float b = __uint_as_float(u & 0xFFFF0000u);
            s += a * a + b * b;
        }
    }
    s = wave_sum(s);
    if (l == 0) { if (isOut) sq_out[r] = s; else sq_enc[r - N_SEC * BDIM] = s; }
}

// 128x128 tile, 4 waves 2x2, BK=32. 4-buffer counted-vmcnt pipeline:
// prologue stages tiles 0..3 (16 loads/wave); step kt: vmcnt(12) -> barrier
// -> compute(kt&3) -> stage tile kt+3 into buf (kt+3)&3. The re-staged buffer
// was last read at step kt-1; the top-of-step barrier orders that (1 barrier).
// XOR chunk swizzle via pre-swizzled global source. Per-block partial output.
template<int MODE>
__global__ void gram4_k(const unsigned short* __restrict__ Xb, const float* __restrict__ sqv,
                        const float* __restrict__ dsent_r, float* __restrict__ dsent_w,
                        float* __restrict__ partials) {
    int n, tile;
    if (MODE == 1) {
        int g = blockIdx.x;           // 0..1151
        int xcd = g & 7, local = g >> 3;
        n = xcd * 4 + local / 36;     // 4 consecutive n per XCD -> L2 locality
        tile = local % 36;
    } else { n = 0; tile = blockIdx.x; }
    int idx = tile, ti = 0;
    while (idx >= 8 - ti) { idx -= 8 - ti; ti++; }
    int tj = ti + idx;
    const unsigned short* Xn = Xb + (size_t)n * BDIM * DDIM;
    const float* sqn = sqv + n * BDIM;
    int i0 = ti * 128, j0 = tj * 128;
    bool diag = (ti == tj);

    __shared__ __align__(16) unsigned short Ash[4][4096];   // 4 x 8KB
    __shared__ __align__(16) unsigned short Bsh[4][4096];
    __shared__ float red[4];

    int t = threadIdx.x, wid = t >> 6, l = t & 63;
    int wr = wid >> 1, wc = wid & 1;
    bool dead = diag && (wr > wc);
    int cg = l >> 4, lr = l & 15;

    f32x4 acc[4][4];
    #pragma unroll
    for (int a = 0; a < 4; a++)
        #pragma unroll
        for (int c = 0; c < 4; c++) acc[a][c] = f32x4{0.f, 0.f, 0.f, 0.f};

    int rs = wid * 16 + (l >> 2);
    int cgs = (l & 3) ^ ((rs >> 1) & 3);
    const unsigned short* gA0 = Xn + (size_t)(i0 + rs) * DDIM + cgs * 8;
    const unsigned short* gA1 = gA0 + (size_t)64 * DDIM;
    const unsigned short* gB0 = Xn + (size_t)(j0 + rs) * DDIM + cgs * 8;
    const unsigned short* gB1 = gB0 + (size_t)64 * DDIM;

    auto stage = [&](int buf, int kt) {      // 4 VMEM ops per wave
        int ko = kt * 32;
        gload16(gA0 + ko, &Ash[buf][wid * 512]);
        gload16(gA1 + ko, &Ash[buf][2048 + wid * 512]);
        gload16(gB0 + ko, &Bsh[buf][wid * 512]);
        gload16(gB1 + ko, &Bsh[buf][2048 + wid * 512]);
    };
    auto compute = [&](int buf) {
        if (dead) return;
        bf16x8 af[4], bfr[4];
        #pragma unroll
        for (int f = 0; f < 4; f++) {
            int ra = wr * 64 + f * 16 + lr;
            af[f] = *(const bf16x8*)&Ash[buf][ra * 32 + ((cg ^ ((ra >> 1) & 3)) * 8)];
            int rb = wc * 64 + f * 16 + lr;
            bfr[f] = *(const bf16x8*)&Bsh[buf][rb * 32 + ((cg ^ ((rb >> 1) & 3)) * 8)];
        }
        #pragma unroll
        for (int fi = 0; fi < 4; fi++)
            #pragma unroll
            for (int fj = 0; fj < 4; fj++) {
                if (diag && wr == wc && fj < fi) continue;
                acc[fi][fj] = mfma16(af[fi], bfr[fj], acc[fi][fj]);
            }
    };

    stage(0, 0); stage(1, 1); stage(2, 2); stage(3, 3);   // 16 outstanding
    for (int kt = 0; kt < 32; ++kt) {
        WAITVM(12);                  // own tile-kt loads landed (oldest 4 of 16)
        pipe_barrier();              // all waves' tile-kt loads landed
        compute(kt & 3);
        int nx = (kt + 3 < 31) ? kt + 3 : 31;   // clamp: keeps 4-loads/iter uniform
        stage((kt + 3) & 3, nx);
    }
    asm volatile("s_waitcnt vmcnt(0)" ::: "memory");   // drain stale DMA before exit

    float lsum = 0.f;
    if (!dead) {
        #pragma unroll
        for (int fi = 0; fi < 4; fi++) {
            #pragma unroll
            for (int fj = 0; fj < 4; fj++) {
                if (diag && wr == wc && fj < fi) continue;
                int jg = j0 + wc * 64 + fj * 16 + lr;
                #pragma unroll
                for (int e = 0; e < 4; e++) {
                    int ig = i0 + wr * 64 + fi * 16 + cg * 4 + e;
                    float g = acc[fi][fj][e];
                    float d2 = sqn[ig] + sqn[jg] - 2.f * g;
                    float d = sqrtf(fmaxf(d2, 0.f) + 1e-12f);
                    if (MODE == 0) {
                        dsent_w[(size_t)ig * BDIM + jg] = d;
                    } else {
                        if (!diag || jg > ig) {
                            float diff = d - dsent_r[(size_t)ig * BDIM + jg];
                            lsum += diff * diff;
                        }
                    }
                }
            }
        }
    }
    if (MODE == 1) {                 // per-block reduce, ONE plain store (no atomics)
        lsum = wave_sum(lsum * 2.f);
        if (l == 0) red[wid] = lsum;
        __syncthreads();
        if (t == 0) partials[blockIdx.x] = red[0] + red[1] + red[2] + red[3];
    }
}

// Batched per-b 32x32 gram, 2-phase dbuf. Per-block partial output, no atomics.
__global__ void secret4_k(const unsigned short* __restrict__ Xb,
                          const float* __restrict__ sq_out, float* __restrict__ partials) {
    __shared__ __align__(16) unsigned short S[2][32 * 4 * 128];
    __shared__ float red[4];
    int t = threadIdx.x, wid = t >> 6, l = t & 63;
    int b0 = blockIdx.x * 4;
    int cg = l >> 4, lr = l & 15;
    f32x4 a00 = {0.f,0.f,0.f,0.f}, a01 = {0.f,0.f,0.f,0.f}, a11 = {0.f,0.f,0.f,0.f};

    auto stage = [&](int buf, int kt) {
        #pragma unroll
        for (int m = 0; m < 8; ++m) {
            int n = m * 4 + wid;
            gload16(Xb + ((size_t)(n * BDIM + b0 + cg)) * DDIM + kt * 128 + ((lr ^ (n & 7)) * 8),
                    &S[buf][n * 512]);
        }
    };
    auto compute = [&](int buf) {
        #pragma unroll
        for (int k2 = 0; k2 < 4; ++k2) {
            int cs = k2 * 4 + cg;
            int cl = (cs ^ (lr & 7)) * 8;
            bf16x8 u0 = *(const bf16x8*)&S[buf][lr * 512 + wid * 128 + cl];
            bf16x8 u1 = *(const bf16x8*)&S[buf][(16 + lr) * 512 + wid * 128 + cl];
            a00 = mfma16(u0, u0, a00);
            a01 = mfma16(u0, u1, a01);
            a11 = mfma16(u1, u1, a11);
        }
    };

    stage(0, 0);
    __syncthreads();
    for (int kt = 0; kt < 6; kt += 2) {
        stage(1, kt + 1);
        compute(0);
        __syncthreads();
        stage(0, kt + 2);
        compute(1);
        __syncthreads();
    }
    stage(1, 7);
    compute(0);
    __syncthreads();
    compute(1);

    float lsum = 0.f;
    int b = b0 + wid;
    auto proc = [&](const f32x4& acc, int rb, int cb) {
        #pragma unroll
        for (int e = 0; e < 4; e++) {
            int i = rb * 16 + cg * 4 + e;
            int j = cb * 16 + lr;
            if (j > i) {
                float d2 = sq_out[(size_t)i * BDIM + b] + sq_out[(size_t)j * BDIM + b] - 2.f * acc[e];
                float d = sqrtf(fmaxf(d2, 0.f) + 1e-12f);
                lsum += fmaxf(1.f - d, 0.f);
            }
        }
    };
    proc(a00, 0, 0); proc(a01, 0, 1); proc(a11, 1, 1);
    lsum = wave_sum(lsum);
    if (l == 0) red[wid] = lsum;
    __syncthreads();
    if (t == 0) partials[blockIdx.x] = red[0] + red[1] + red[2] + red[3];
}

// Reduce partials (1152 sentence + 256 secret) and write the 3 outputs.
__global__ void fin2_k(const float* __restrict__ ps, const float* __restrict__ psec,
                       float* __restrict__ out) {
    __shared__ float red[16];
    int t = threadIdx.x;
    float s = 0.f;
    for (int i = t; i < 36 * N_SEC; i += 256) s += ps[i];
    float s2 = psec[t];                       // exactly 256 partials
    s = wave_sum(s);
    s2 = wave_sum(s2);
    if ((t & 63) == 0) { red[t >> 6] = s; red[8 + (t >> 6)] = s2; }
    __syncthreads();
    if (t == 0) {
        float a = red[0] + red[1] + red[2] + red[3];
        float b = red[8] + red[9] + red[10] + red[11];
        float sl = a * (1.0f / 33554432.0f);           // / (N*B*B)
        float sec = b * (1.0f / (1024.0f * 496.0f));   // / B / n_pairs
        out[0] = 0.5f * sl + 0.5f * sec;
        out[1] = sl;
        out[2] = sec;
    }
}

// ---------------------------------------------------------------------------
// Path B (fallback, round-0 known-good): fp32 reads + in-loop convert.
// ---------------------------------------------------------------------------

__global__ void norms_k(const float* __restrict__ outp, const float* __restrict__ enc,
                        float* __restrict__ sq_out, float* __restrict__ sq_enc) {
    int wid = threadIdx.x >> 6, l = threadIdx.x & 63;
    int r = blockIdx.x * 4 + wid;
    const float* src = (r < N_SEC * BDIM) ? (outp + (size_t)r * DDIM)
                                          : (enc + (size_t)(r - N_SEC * BDIM) * DDIM);
    float s = 0.f;
    #pragma unroll
    for (int q = 0; q < 4; q++) {
        float4 v = reinterpret_cast<const float4*>(src)[l + q * 64];
        unsigned u0 = pk2(v.x, v.y), u1 = pk2(v.z, v.w);
        float a = __uint_as_float(u0 << 16), b = __uint_as_float(u0 & 0xFFFF0000u);
        float c = __uint_as_float(u1 << 16), d = __uint_as_float(u1 & 0xFFFF0000u);
        s += a * a + b * b + c * c + d * d;
    }
    s = wave_sum(s);
    if (l == 0) { if (r < N_SEC * BDIM) sq_out[r] = s; else sq_enc[r - N_SEC * BDIM] = s; }
}

template<int MODE>
__global__ void gram_k(const float* __restrict__ X, const float* __restrict__ sqv,
                       const float* __restrict__ dsent_r, float* __restrict__ dsent_w,
                       float* __restrict__ accum) {
    int idx = blockIdx.x, ti = 0;
    while (idx >= 8 - ti) { idx -= 8 - ti; ti++; }
    int tj = ti + idx;
    int n = (MODE == 1) ? blockIdx.y : 0;
    const float* Xn = X + (size_t)n * BDIM * DDIM;
    const float* sqn = sqv + n * BDIM;
    int i0 = ti * 128, j0 = tj * 128;
    bool diag = (ti == tj);
    __shared__ __align__(16) unsigned short Ash[128 * 32];
    __shared__ __align__(16) unsigned short Bsh[128 * 32];
    int t = threadIdx.x, wid = t >> 6, l = t & 63;
    int wr = wid >> 1, wc = wid & 1;
    bool dead = diag && (wr > wc);
    int cg = l >> 4, lr = l & 15;
    f32x4 acc[4][4];
    #pragma unroll
    for (int a = 0; a < 4; a++)
        #pragma unroll
        for (int c = 0; c < 4; c++) acc[a][c] = f32x4{0.f, 0.f, 0.f, 0.f};
    int r0 = t >> 2, c0 = t & 3;
    int swz0 = (c0 ^ (r0 & 3)) * 8;
    int off0 = r0 * 32 + swz0;
    int off1 = (r0 + 64) * 32 + swz0;
    for (int kt = 0; kt < DDIM / 32; ++kt) {
        int k0 = kt * 32;
        const float4* pa0 = (const float4*)(Xn + (size_t)(i0 + r0) * DDIM + k0 + c0 * 8);
        const float4* pa1 = (const float4*)(Xn + (size_t)(i0 + r0 + 64) * DDIM + k0 + c0 * 8);
        const float4* pb0 = (const float4*)(Xn + (size_t)(j0 + r0) * DDIM + k0 + c0 * 8);
        const float4* pb1 = (const float4*)(Xn + (size_t)(j0 + r0 + 64) * DDIM + k0 + c0 * 8);
        float4 a00 = pa0[0], a01 = pa0[1];
        float4 a10 = pa1[0], a11 = pa1[1];
        float4 b00 = pb0[0], b01 = pb0[1];
        float4 b10 = pb1[0], b11 = pb1[1];
        __syncthreads();
        *(i32x4*)&Ash[off0] = pack8(a00, a01);
        *(i32x4*)&Ash[off1] = pack8(a10, a11);
        *(i32x4*)&Bsh[off0] = pack8(b00, b01);
        *(i32x4*)&Bsh[off1] = pack8(b10, b11);
        __syncthreads();
        if (!dead) {
            bf16x8 af[4], bfr[4];
            #pragma unroll
            for (int f = 0; f < 4; f++) {
                int ra = wr * 64 + f * 16 + lr;
                af[f] = *(const bf16x8*)&Ash[ra * 32 + ((cg ^ (ra & 3)) * 8)];
                int rb = wc * 64 + f * 16 + lr;
                bfr[f] = *(const bf16x8*)&Bsh[rb * 32 + ((cg ^ (rb & 3)) * 8)];
            }
            #pragma unroll
            for (int fi = 0; fi < 4; fi++)
                #pragma unroll
                for (int fj = 0; fj < 4; fj++) {
                    if (diag && wr == wc && fj < fi) continue;
                    acc[fi][fj] = mfma16(af[fi], bfr[fj], acc[fi][fj]);
                }
        }
    }
    if (!dead) {
        float lsum = 0.f;
        #pragma unroll
        for (int fi = 0; fi < 4; fi++) {
            #pragma unroll
            for (int fj = 0; fj < 4; fj++) {
                if (diag && wr == wc && fj < fi) continue;
                int jg = j0 + wc * 64 + fj * 16 + lr;
                #pragma unroll
                for (int e = 0; e < 4; e++) {
                    int ig = i0 + wr * 64 + fi * 16 + cg * 4 + e;
                    float g = acc[fi][fj][e];
                    float d2 = sqn[ig] + sqn[jg] - 2.f * g;
                    float d = sqrtf(fmaxf(d2, 0.f) + 1e-12f);
                    if (MODE == 0) {
                        dsent_w[(size_t)ig * BDIM + jg] = d;
                    } else {
                        if (!diag || jg > ig) {
                            float diff = d - dsent_r[(size_t)ig * BDIM + jg];
                            lsum += diff * diff;
                        }
                    }
                }
            }
        }
        if (MODE == 1) {
            lsum = wave_sum(lsum * 2.f);
            if (l == 0) atomicAdd(accum, lsum);
        }
    }
}

__global__ void secret_k(const float* __restrict__ X, const float* __restrict__ sq_out,
                         float* __restrict__ accum) {
    int wid = threadIdx.x >> 6, l = threadIdx.x & 63;
    int b = blockIdx.x * 4 + wid;
    int cg = l >> 4, lr = l & 15;
    f32x4 a00 = {0.f,0.f,0.f,0.f}, a01 = {0.f,0.f,0.f,0.f}, a11 = {0.f,0.f,0.f,0.f};
    for (int kt = 0; kt < 32; ++kt) {
        int k0 = kt * 32 + cg * 8;
        const float4* p0 = (const float4*)(X + ((size_t)lr * BDIM + b) * DDIM + k0);
        const float4* p1 = (const float4*)(X + ((size_t)(16 + lr) * BDIM + b) * DDIM + k0);
        union { i32x4 i; bf16x8 s; } u0, u1;
        u0.i = pack8(p0[0], p0[1]);
        u1.i = pack8(p1[0], p1[1]);
        a00 = mfma16(u0.s, u0.s, a00);
        a01 = mfma16(u0.s, u1.s, a01);
        a11 = mfma16(u1.s, u1.s, a11);
    }
    float lsum = 0.f;
    auto proc = [&](const f32x4& acc, int rb, int cb) {
        #pragma unroll
        for (int e = 0; e < 4; e++) {
            int i = rb * 16 + cg * 4 + e;
            int j = cb * 16 + lr;
            if (j > i) {
                float d2 = sq_out[(size_t)i * BDIM + b] + sq_out[(size_t)j * BDIM + b] - 2.f * acc[e];
                float d = sqrtf(fmaxf(d2, 0.f) + 1e-12f);
                lsum += fmaxf(1.f - d, 0.f);
            }
        }
    };
    proc(a00, 0, 0); proc(a01, 0, 1); proc(a11, 1, 1);
    lsum = wave_sum(lsum);
    if (l == 0) atomicAdd(accum, lsum);
}

__global__ void init_k(float* sums) { sums[threadIdx.x] = 0.f; }

__global__ void fin_k(const float* __restrict__ sums, float* __restrict__ out) {
    float sl = sums[0] * (1.0f / 33554432.0f);
    float sec = sums[1] * (1.0f / (1024.0f * 496.0f));
    out[0] = 0.5f * sl + 0.5f * sec;
    out[1] = sl;
    out[2] = sec;
}

extern "C" void kernel_launch(void* const* d_in, const int* in_sizes, int n_in,
                              void* d_out, int out_size, void* d_ws, size_t ws_size,
                              hipStream_t stream) {
    const float* outputs = (const float*)d_in[0];   // [32,1024,1024] f32
    const float* enc     = (const float*)d_in[1];   // [1024,1024] f32
    float* out = (float*)d_out;                     // 3 floats

    // Path A ws layout (floats): ps[1152] pad to 1536 | psec[256] pad to 2048 |
    //   sq_out[32768] | sq_enc[1024] | dsent[1M] | then bf16: Xbf, Ebf
    float* ps     = (float*)d_ws;
    float* psec   = ps + 1536;
    float* sq_out = ps + 2048;
    float* sq_enc = sq_out + N_SEC * BDIM;
    float* dsent  = sq_enc + BDIM;
    unsigned short* Xbf = (unsigned short*)(dsent + (size_t)BDIM * BDIM);
    unsigned short* Ebf = Xbf + (size_t)N_SEC * BDIM * DDIM;

    const size_t NEED = 4 * (2048 + (size_t)N_SEC * BDIM + BDIM + (size_t)BDIM * BDIM)
                      + 2 * ((size_t)N_SEC * BDIM * DDIM + (size_t)BDIM * DDIM);

    if (ws_size >= NEED) {
        hipLaunchKernelGGL(prep_k, dim3((N_SEC * BDIM + BDIM) / 4), dim3(256), 0, stream,
                           outputs, enc, Xbf, Ebf, sq_out, sq_enc);
        hipLaunchKernelGGL((gram4_k<0>), dim3(36), dim3(256), 0, stream,
                           Ebf, sq_enc, (const float*)nullptr, dsent, (float*)nullptr);
        hipLaunchKernelGGL((gram4_k<1>), dim3(36 * N_SEC), dim3(256), 0, stream,
                           Xbf, sq_out, (const float*)dsent, (float*)nullptr, ps);
        hipLaunchKernelGGL(secret4_k, dim3(BDIM / 4), dim3(256), 0, stream,
                           Xbf, sq_out, psec);
        hipLaunchKernelGGL(fin2_k, dim3(1), dim3(256), 0, stream, ps, psec, out);
    } else {
        float* sums = (float*)d_ws;
        float* fsq_out = sums + 64;
        float* fsq_enc = fsq_out + N_SEC * BDIM;
        float* fdsent  = fsq_enc + BDIM;
        hipLaunchKernelGGL(init_k, dim3(1), dim3(2), 0, stream, sums);
        hipLaunchKernelGGL(norms_k, dim3((N_SEC * BDIM + BDIM) / 4), dim3(256), 0, stream,
                           outputs, enc, fsq_out, fsq_enc);
        hipLaunchKernelGGL((gram_k<0>), dim3(36), dim3(256), 0, stream,
                           enc, fsq_enc, (const float*)nullptr, fdsent, (float*)nullptr);
        hipLaunchKernelGGL((gram_k<1>), dim3(36, N_SEC), dim3(256), 0, stream,
                           outputs, fsq_out, (const float*)fdsent, (float*)nullptr, &sums[0]);
        hipLaunchKernelGGL(secret_k, dim3(BDIM / 4), dim3(256), 0, stream,
                           outputs, fsq_out, &sums[1]);
        hipLaunchKernelGGL(fin_k, dim3(1), dim3(1), 0, stream, sums, out);
    }
}

// Round 5
// 152.974 us; speedup vs baseline: 1.8995x; 1.1337x over previous
//
#include <hip/hip_runtime.h>
#include <hip/hip_bf16.h>

#define N_SEC 32
#define BDIM 1024
#define DDIM 1024

typedef __attribute__((ext_vector_type(8))) short bf16x8;
typedef __attribute__((ext_vector_type(4))) float f32x4;
typedef __attribute__((ext_vector_type(4))) int i32x4;

#define WAITVM(n) asm volatile("s_waitcnt vmcnt(" #n ")" ::: "memory")

__device__ __forceinline__ void pipe_barrier() {
    __builtin_amdgcn_s_barrier();
    asm volatile("" ::: "memory");
    __builtin_amdgcn_sched_barrier(0);
}

__device__ __forceinline__ unsigned pk2(float a, float b) {
    union { __hip_bfloat162 h; unsigned u; } cv;
    cv.h = __float22bfloat162_rn(make_float2(a, b));
    return cv.u;
}

__device__ __forceinline__ i32x4 pack8(float4 a, float4 b) {
    i32x4 r;
    r[0] = pk2(a.x, a.y); r[1] = pk2(a.z, a.w);
    r[2] = pk2(b.x, b.y); r[3] = pk2(b.z, b.w);
    return r;
}

__device__ __forceinline__ f32x4 mfma16(bf16x8 a, bf16x8 b, f32x4 c) {
    return __builtin_amdgcn_mfma_f32_16x16x32_bf16(a, b, c, 0, 0, 0);
}

__device__ __forceinline__ float wave_sum(float v) {
    #pragma unroll
    for (int off = 32; off > 0; off >>= 1) v += __shfl_down(v, off, 64);
    return v;
}

__device__ __forceinline__ void gload16(const unsigned short* g, unsigned short* l) {
    __builtin_amdgcn_global_load_lds(
        (const __attribute__((address_space(1))) unsigned int*)g,
        (__attribute__((address_space(3))) unsigned int*)l, 16, 0, 0);
}

// ---------------------------------------------------------------------------
// Path A: prep, gram5 (3-buffer depth-2 counted-vmcnt, 48KB LDS -> 3 blk/CU),
// secret4, fin2.
// ---------------------------------------------------------------------------

__global__ void prep_k(const float* __restrict__ outp, const float* __restrict__ enc,
                       unsigned short* __restrict__ Xb, unsigned short* __restrict__ Eb,
                       float* __restrict__ sq_out, float* __restrict__ sq_enc) {
    int wid = threadIdx.x >> 6, l = threadIdx.x & 63;
    int r = blockIdx.x * 4 + wid;
    bool isOut = r < N_SEC * BDIM;
    const float* src = isOut ? (outp + (size_t)r * DDIM)
                             : (enc + (size_t)(r - N_SEC * BDIM) * DDIM);
    unsigned short* dst = isOut ? (Xb + (size_t)r * DDIM)
                                : (Eb + (size_t)(r - N_SEC * BDIM) * DDIM);
    const float4* s4 = (const float4*)src;
    float s = 0.f;
    #pragma unroll
    for (int h = 0; h < 2; ++h) {
        int c = l + h * 64;
        float4 v0 = s4[2 * c], v1 = s4[2 * c + 1];
        i32x4 p = pack8(v0, v1);
        *(i32x4*)&dst[c * 8] = p;
        #pragma unroll
        for (int e = 0; e < 4; ++e) {
            unsigned u = (unsigned)p[e];
            float a = __uint_as_float(u << 16);
            float b = __uint_as_float(u & 0xFFFF0000u);
            s += a * a + b * b;
        }
    }
    s = wave_sum(s);
    if (l == 0) { if (isOut) sq_out[r] = s; else sq_enc[r - N_SEC * BDIM] = s; }
}

// 128x128 tile, 4 waves 2x2, BK=32. 3-buffer depth-2 pipeline:
// prologue stages tiles 0,1 (8 loads/wave). Each step: barrier (all waves'
// reads of the victim buffer completed - enforced because each wave's MFMAs
// consumed those ds_reads via lgkmcnt before reaching the barrier) -> stage
// tile c+2 into buffer (c+2)%3 -> vmcnt(8) (tile-c loads landed, 8 newer in
// flight) -> compute(c%3). One barrier per step; vmcnt never drained in loop.
template<int MODE>
__global__ void gram5_k(const unsigned short* __restrict__ Xb, const float* __restrict__ sqv,
                        const float* __restrict__ dsent_r, float* __restrict__ dsent_w,
                        float* __restrict__ partials) {
    int n, tile;
    if (MODE == 1) {
        int g = blockIdx.x;           // 0..1151
        int xcd = g & 7, local = g >> 3;
        n = xcd * 4 + local / 36;     // 4 consecutive n per XCD -> L2 locality
        tile = local % 36;
    } else { n = 0; tile = blockIdx.x; }
    int idx = tile, ti = 0;
    while (idx >= 8 - ti) { idx -= 8 - ti; ti++; }
    int tj = ti + idx;
    const unsigned short* Xn = Xb + (size_t)n * BDIM * DDIM;
    const float* sqn = sqv + n * BDIM;
    int i0 = ti * 128, j0 = tj * 128;
    bool diag = (ti == tj);

    __shared__ __align__(16) unsigned short Ash[3][4096];   // 3 x 8KB
    __shared__ __align__(16) unsigned short Bsh[3][4096];
    __shared__ float red[4];

    int t = threadIdx.x, wid = t >> 6, l = t & 63;
    int wr = wid >> 1, wc = wid & 1;
    bool dead = diag && (wr > wc);
    int cg = l >> 4, lr = l & 15;

    f32x4 acc[4][4];
    #pragma unroll
    for (int a = 0; a < 4; a++)
        #pragma unroll
        for (int c = 0; c < 4; c++) acc[a][c] = f32x4{0.f, 0.f, 0.f, 0.f};

    // loop-invariant LDS element offsets for the 8 fragment reads
    int eoffA[4], eoffB[4];
    #pragma unroll
    for (int f = 0; f < 4; f++) {
        int ra = wr * 64 + f * 16 + lr;
        eoffA[f] = ra * 32 + ((cg ^ ((ra >> 1) & 3)) * 8);
        int rb = wc * 64 + f * 16 + lr;
        eoffB[f] = rb * 32 + ((cg ^ ((rb >> 1) & 3)) * 8);
    }

    int rs = wid * 16 + (l >> 2);
    int cgs = (l & 3) ^ ((rs >> 1) & 3);
    const unsigned short* gA0 = Xn + (size_t)(i0 + rs) * DDIM + cgs * 8;
    const unsigned short* gA1 = gA0 + (size_t)64 * DDIM;
    const unsigned short* gB0 = Xn + (size_t)(j0 + rs) * DDIM + cgs * 8;
    const unsigned short* gB1 = gB0 + (size_t)64 * DDIM;

    auto stage = [&](int buf, int kt) {      // 4 VMEM ops per wave
        int ko = kt * 32;
        gload16(gA0 + ko, &Ash[buf][wid * 512]);
        gload16(gA1 + ko, &Ash[buf][2048 + wid * 512]);
        gload16(gB0 + ko, &Bsh[buf][wid * 512]);
        gload16(gB1 + ko, &Bsh[buf][2048 + wid * 512]);
    };
    auto compute = [&](int buf) {            // buf is literal at every call site
        if (dead) return;
        bf16x8 af[4], bfr[4];
        #pragma unroll
        for (int f = 0; f < 4; f++) {
            af[f]  = *(const bf16x8*)&Ash[buf][eoffA[f]];
            bfr[f] = *(const bf16x8*)&Bsh[buf][eoffB[f]];
        }
        #pragma unroll
        for (int fi = 0; fi < 4; fi++)
            #pragma unroll
            for (int fj = 0; fj < 4; fj++) {
                if (diag && wr == wc && fj < fi) continue;
                acc[fi][fj] = mfma16(af[fi], bfr[fj], acc[fi][fj]);
            }
    };

#define GSTEP(NB, CB) do {                       \
        pipe_barrier();                          \
        int nx = c + 2; if (nx > 31) nx = 31;    \
        stage(NB, nx);                           \
        WAITVM(8);                               \
        compute(CB);                             \
        ++c; } while (0)

    stage(0, 0); stage(1, 1);                    // 8 outstanding
    int c = 0;
    #pragma unroll 1
    for (int it = 0; it < 10; ++it) {            // computes tiles 0..29
        GSTEP(2, 0);
        GSTEP(0, 1);
        GSTEP(1, 2);
    }
    GSTEP(2, 0);                                 // tile 30
    GSTEP(0, 1);                                 // tile 31
#undef GSTEP
    asm volatile("s_waitcnt vmcnt(0)" ::: "memory");   // drain before exit

    float lsum = 0.f;
    if (!dead) {
        #pragma unroll
        for (int fi = 0; fi < 4; fi++) {
            #pragma unroll
            for (int fj = 0; fj < 4; fj++) {
                if (diag && wr == wc && fj < fi) continue;
                int jg = j0 + wc * 64 + fj * 16 + lr;
                #pragma unroll
                for (int e = 0; e < 4; e++) {
                    int ig = i0 + wr * 64 + fi * 16 + cg * 4 + e;
                    float g = acc[fi][fj][e];
                    float d2 = sqn[ig] + sqn[jg] - 2.f * g;
                    float d = sqrtf(fmaxf(d2, 0.f) + 1e-12f);
                    if (MODE == 0) {
                        dsent_w[(size_t)ig * BDIM + jg] = d;
                    } else {
                        if (!diag || jg > ig) {
                            float diff = d - dsent_r[(size_t)ig * BDIM + jg];
                            lsum += diff * diff;
                        }
                    }
                }
            }
        }
    }
    if (MODE == 1) {
        lsum = wave_sum(lsum * 2.f);
        if (l == 0) red[wid] = lsum;
        __syncthreads();
        if (t == 0) partials[blockIdx.x] = red[0] + red[1] + red[2] + red[3];
    }
}

// Batched per-b 32x32 gram, 2-phase dbuf. Per-block partial output.
__global__ void secret4_k(const unsigned short* __restrict__ Xb,
                          const float* __restrict__ sq_out, float* __restrict__ partials) {
    __shared__ __align__(16) unsigned short S[2][32 * 4 * 128];
    __shared__ float red[4];
    int t = threadIdx.x, wid = t >> 6, l = t & 63;
    int b0 = blockIdx.x * 4;
    int cg = l >> 4, lr = l & 15;
    f32x4 a00 = {0.f,0.f,0.f,0.f}, a01 = {0.f,0.f,0.f,0.f}, a11 = {0.f,0.f,0.f,0.f};

    auto stage = [&](int buf, int kt) {
        #pragma unroll
        for (int m = 0; m < 8; ++m) {
            int n = m * 4 + wid;
            gload16(Xb + ((size_t)(n * BDIM + b0 + cg)) * DDIM + kt * 128 + ((lr ^ (n & 7)) * 8),
                    &S[buf][n * 512]);
        }
    };
    auto compute = [&](int buf) {
        #pragma unroll
        for (int k2 = 0; k2 < 4; ++k2) {
            int cs = k2 * 4 + cg;
            int cl = (cs ^ (lr & 7)) * 8;
            bf16x8 u0 = *(const bf16x8*)&S[buf][lr * 512 + wid * 128 + cl];
            bf16x8 u1 = *(const bf16x8*)&S[buf][(16 + lr) * 512 + wid * 128 + cl];
            a00 = mfma16(u0, u0, a00);
            a01 = mfma16(u0, u1, a01);
            a11 = mfma16(u1, u1, a11);
        }
    };

    stage(0, 0);
    __syncthreads();
    for (int kt = 0; kt < 6; kt += 2) {
        stage(1, kt + 1);
        compute(0);
        __syncthreads();
        stage(0, kt + 2);
        compute(1);
        __syncthreads();
    }
    stage(1, 7);
    compute(0);
    __syncthreads();
    compute(1);

    float lsum = 0.f;
    int b = b0 + wid;
    auto proc = [&](const f32x4& acc, int rb, int cb) {
        #pragma unroll
        for (int e = 0; e < 4; e++) {
            int i = rb * 16 + cg * 4 + e;
            int j = cb * 16 + lr;
            if (j > i) {
                float d2 = sq_out[(size_t)i * BDIM + b] + sq_out[(size_t)j * BDIM + b] - 2.f * acc[e];
                float d = sqrtf(fmaxf(d2, 0.f) + 1e-12f);
                lsum += fmaxf(1.f - d, 0.f);
            }
        }
    };
    proc(a00, 0, 0); proc(a01, 0, 1); proc(a11, 1, 1);
    lsum = wave_sum(lsum);
    if (l == 0) red[wid] = lsum;
    __syncthreads();
    if (t == 0) partials[blockIdx.x] = red[0] + red[1] + red[2] + red[3];
}

__global__ void fin2_k(const float* __restrict__ ps, const float* __restrict__ psec,
                       float* __restrict__ out) {
    __shared__ float red[16];
    int t = threadIdx.x;
    float s = 0.f;
    for (int i = t; i < 36 * N_SEC; i += 256) s += ps[i];
    float s2 = psec[t];
    s = wave_sum(s);
    s2 = wave_sum(s2);
    if ((t & 63) == 0) { red[t >> 6] = s; red[8 + (t >> 6)] = s2; }
    __syncthreads();
    if (t == 0) {
        float a = red[0] + red[1] + red[2] + red[3];
        float b = red[8] + red[9] + red[10] + red[11];
        float sl = a * (1.0f / 33554432.0f);
        float sec = b * (1.0f / (1024.0f * 496.0f));
        out[0] = 0.5f * sl + 0.5f * sec;
        out[1] = sl;
        out[2] = sec;
    }
}

// ---------------------------------------------------------------------------
// Path B (fallback, known-good): fp32 reads + in-loop convert.
// ---------------------------------------------------------------------------

__global__ void norms_k(const float* __restrict__ outp, const float* __restrict__ enc,
                        float* __restrict__ sq_out, float* __restrict__ sq_enc) {
    int wid = threadIdx.x >> 6, l = threadIdx.x & 63;
    int r = blockIdx.x * 4 + wid;
    const float* src = (r < N_SEC * BDIM) ? (outp + (size_t)r * DDIM)
                                          : (enc + (size_t)(r - N_SEC * BDIM) * DDIM);
    float s = 0.f;
    #pragma unroll
    for (int q = 0; q < 4; q++) {
        float4 v = reinterpret_cast<const float4*>(src)[l + q * 64];
        unsigned u0 = pk2(v.x, v.y), u1 = pk2(v.z, v.w);
        float a = __uint_as_float(u0 << 16), b = __uint_as_float(u0 & 0xFFFF0000u);
        float c = __uint_as_float(u1 << 16), d = __uint_as_float(u1 & 0xFFFF0000u);
        s += a * a + b * b + c * c + d * d;
    }
    s = wave_sum(s);
    if (l == 0) { if (r < N_SEC * BDIM) sq_out[r] = s; else sq_enc[r - N_SEC * BDIM] = s; }
}

template<int MODE>
__global__ void gram_k(const float* __restrict__ X, const float* __restrict__ sqv,
                       const float* __restrict__ dsent_r, float* __restrict__ dsent_w,
                       float* __restrict__ accum) {
    int idx = blockIdx.x, ti = 0;
    while (idx >= 8 - ti) { idx -= 8 - ti; ti++; }
    int tj = ti + idx;
    int n = (MODE == 1) ? blockIdx.y : 0;
    const float* Xn = X + (size_t)n * BDIM * DDIM;
    const float* sqn = sqv + n * BDIM;
    int i0 = ti * 128, j0 = tj * 128;
    bool diag = (ti == tj);
    __shared__ __align__(16) unsigned short Ash[128 * 32];
    __shared__ __align__(16) unsigned short Bsh[128 * 32];
    int t = threadIdx.x, wid = t >> 6, l = t & 63;
    int wr = wid >> 1, wc = wid & 1;
    bool dead = diag && (wr > wc);
    int cg = l >> 4, lr = l & 15;
    f32x4 acc[4][4];
    #pragma unroll
    for (int a = 0; a < 4; a++)
        #pragma unroll
        for (int c = 0; c < 4; c++) acc[a][c] = f32x4{0.f, 0.f, 0.f, 0.f};
    int r0 = t >> 2, c0 = t & 3;
    int swz0 = (c0 ^ (r0 & 3)) * 8;
    int off0 = r0 * 32 + swz0;
    int off1 = (r0 + 64) * 32 + swz0;
    for (int kt = 0; kt < DDIM / 32; ++kt) {
        int k0 = kt * 32;
        const float4* pa0 = (const float4*)(Xn + (size_t)(i0 + r0) * DDIM + k0 + c0 * 8);
        const float4* pa1 = (const float4*)(Xn + (size_t)(i0 + r0 + 64) * DDIM + k0 + c0 * 8);
        const float4* pb0 = (const float4*)(Xn + (size_t)(j0 + r0) * DDIM + k0 + c0 * 8);
        const float4* pb1 = (const float4*)(Xn + (size_t)(j0 + r0 + 64) * DDIM + k0 + c0 * 8);
        float4 a00 = pa0[0], a01 = pa0[1];
        float4 a10 = pa1[0], a11 = pa1[1];
        float4 b00 = pb0[0], b01 = pb0[1];
        float4 b10 = pb1[0], b11 = pb1[1];
        __syncthreads();
        *(i32x4*)&Ash[off0] = pack8(a00, a01);
        *(i32x4*)&Ash[off1] = pack8(a10, a11);
        *(i32x4*)&Bsh[off0] = pack8(b00, b01);
        *(i32x4*)&Bsh[off1] = pack8(b10, b11);
        __syncthreads();
        if (!dead) {
            bf16x8 af[4], bfr[4];
            #pragma unroll
            for (int f = 0; f < 4; f++) {
                int ra = wr * 64 + f * 16 + lr;
                af[f] = *(const bf16x8*)&Ash[ra * 32 + ((cg ^ (ra & 3)) * 8)];
                int rb = wc * 64 + f * 16 + lr;
                bfr[f] = *(const bf16x8*)&Bsh[rb * 32 + ((cg ^ (rb & 3)) * 8)];
            }
            #pragma unroll
            for (int fi = 0; fi < 4; fi++)
                #pragma unroll
                for (int fj = 0; fj < 4; fj++) {
                    if (diag && wr == wc && fj < fi) continue;
                    acc[fi][fj] = mfma16(af[fi], bfr[fj], acc[fi][fj]);
                }
        }
    }
    if (!dead) {
        float lsum = 0.f;
        #pragma unroll
        for (int fi = 0; fi < 4; fi++) {
            #pragma unroll
            for (int fj = 0; fj < 4; fj++) {
                if (diag && wr == wc && fj < fi) continue;
                int jg = j0 + wc * 64 + fj * 16 + lr;
                #pragma unroll
                for (int e = 0; e < 4; e++) {
                    int ig = i0 + wr * 64 + fi * 16 + cg * 4 + e;
                    float g = acc[fi][fj][e];
                    float d2 = sqn[ig] + sqn[jg] - 2.f * g;
                    float d = sqrtf(fmaxf(d2, 0.f) + 1e-12f);
                    if (MODE == 0) {
                        dsent_w[(size_t)ig * BDIM + jg] = d;
                    } else {
                        if (!diag || jg > ig) {
                            float diff = d - dsent_r[(size_t)ig * BDIM + jg];
                            lsum += diff * diff;
                        }
                    }
                }
            }
        }
        if (MODE == 1) {
            lsum = wave_sum(lsum * 2.f);
            if (l == 0) atomicAdd(accum, lsum);
        }
    }
}

__global__ void secret_k(const float* __restrict__ X, const float* __restrict__ sq_out,
                         float* __restrict__ accum) {
    int wid = threadIdx.x >> 6, l = threadIdx.x & 63;
    int b = blockIdx.x * 4 + wid;
    int cg = l >> 4, lr = l & 15;
    f32x4 a00 = {0.f,0.f,0.f,0.f}, a01 = {0.f,0.f,0.f,0.f}, a11 = {0.f,0.f,0.f,0.f};
    for (int kt = 0; kt < 32; ++kt) {
        int k0 = kt * 32 + cg * 8;
        const float4* p0 = (const float4*)(X + ((size_t)lr * BDIM + b) * DDIM + k0);
        const float4* p1 = (const float4*)(X + ((size_t)(16 + lr) * BDIM + b) * DDIM + k0);
        union { i32x4 i; bf16x8 s; } u0, u1;
        u0.i = pack8(p0[0], p0[1]);
        u1.i = pack8(p1[0], p1[1]);
        a00 = mfma16(u0.s, u0.s, a00);
        a01 = mfma16(u0.s, u1.s, a01);
        a11 = mfma16(u1.s, u1.s, a11);
    }
    float lsum = 0.f;
    auto proc = [&](const f32x4& acc, int rb, int cb) {
        #pragma unroll
        for (int e = 0; e < 4; e++) {
            int i = rb * 16 + cg * 4 + e;
            int j = cb * 16 + lr;
            if (j > i) {
                float d2 = sq_out[(size_t)i * BDIM + b] + sq_out[(size_t)j * BDIM + b] - 2.f * acc[e];
                float d = sqrtf(fmaxf(d2, 0.f) + 1e-12f);
                lsum += fmaxf(1.f - d, 0.f);
            }
        }
    };
    proc(a00, 0, 0); proc(a01, 0, 1); proc(a11, 1, 1);
    lsum = wave_sum(lsum);
    if (l == 0) atomicAdd(accum, lsum);
}

__global__ void init_k(float* sums) { sums[threadIdx.x] = 0.f; }

__global__ void fin_k(const float* __restrict__ sums, float* __restrict__ out) {
    float sl = sums[0] * (1.0f / 33554432.0f);
    float sec = sums[1] * (1.0f / (1024.0f * 496.0f));
    out[0] = 0.5f * sl + 0.5f * sec;
    out[1] = sl;
    out[2] = sec;
}

extern "C" void kernel_launch(void* const* d_in, const int* in_sizes, int n_in,
                              void* d_out, int out_size, void* d_ws, size_t ws_size,
                              hipStream_t stream) {
    const float* outputs = (const float*)d_in[0];   // [32,1024,1024] f32
    const float* enc     = (const float*)d_in[1];   // [1024,1024] f32
    float* out = (float*)d_out;                     // 3 floats

    float* ps     = (float*)d_ws;
    float* psec   = ps + 1536;
    float* sq_out = ps + 2048;
    float* sq_enc = sq_out + N_SEC * BDIM;
    float* dsent  = sq_enc + BDIM;
    unsigned short* Xbf = (unsigned short*)(dsent + (size_t)BDIM * BDIM);
    unsigned short* Ebf = Xbf + (size_t)N_SEC * BDIM * DDIM;

    const size_t NEED = 4 * (2048 + (size_t)N_SEC * BDIM + BDIM + (size_t)BDIM * BDIM)
                      + 2 * ((size_t)N_SEC * BDIM * DDIM + (size_t)BDIM * DDIM);

    if (ws_size >= NEED) {
        hipLaunchKernelGGL(prep_k, dim3((N_SEC * BDIM + BDIM) / 4), dim3(256), 0, stream,
                           outputs, enc, Xbf, Ebf, sq_out, sq_enc);
        hipLaunchKernelGGL((gram5_k<0>), dim3(36), dim3(256), 0, stream,
                           Ebf, sq_enc, (const float*)nullptr, dsent, (float*)nullptr);
        hipLaunchKernelGGL((gram5_k<1>), dim3(36 * N_SEC), dim3(256), 0, stream,
                           Xbf, sq_out, (const float*)dsent, (float*)nullptr, ps);
        hipLaunchKernelGGL(secret4_k, dim3(BDIM / 4), dim3(256), 0, stream,
                           Xbf, sq_out, psec);
        hipLaunchKernelGGL(fin2_k, dim3(1), dim3(256), 0, stream, ps, psec, out);
    } else {
        float* sums = (float*)d_ws;
        float* fsq_out = sums + 64;
        float* fsq_enc = fsq_out + N_SEC * BDIM;
        float* fdsent  = fsq_enc + BDIM;
        hipLaunchKernelGGL(init_k, dim3(1), dim3(2), 0, stream, sums);
        hipLaunchKernelGGL(norms_k, dim3((N_SEC * BDIM + BDIM) / 4), dim3(256), 0, stream,
                           outputs, enc, fsq_out, fsq_enc);
        hipLaunchKernelGGL((gram_k<0>), dim3(36), dim3(256), 0, stream,
                           enc, fsq_enc, (const float*)nullptr, fdsent, (float*)nullptr);
        hipLaunchKernelGGL((gram_k<1>), dim3(36, N_SEC), dim3(256), 0, stream,
                           outputs, fsq_out, (const float*)fdsent, (float*)nullptr, &sums[0]);
        hipLaunchKernelGGL(secret_k, dim3(BDIM / 4), dim3(256), 0, stream,
                           outputs, fsq_out, &sums[1]);
        hipLaunchKernelGGL(fin_k, dim3(1), dim3(1), 0, stream, sums, out);
    }
}